// Round 17
// baseline (196.658 us; speedup 1.0000x reference)
//
#include <hip/hip_runtime.h>

constexpr int NB  = 16;      // batches
constexpr int NP  = 1024;    // points per batch
constexpr int NPT = NB * NP; // 16384
constexpr int KNB = 20;

typedef unsigned short ushortT;
typedef __bf16 bf16x8 __attribute__((ext_vector_type(8)));
typedef _Float16 f16x8 __attribute__((ext_vector_type(8)));
typedef float f32x4 __attribute__((ext_vector_type(4)));

__device__ inline unsigned f2bf_pair(float f0, float f1) {
    unsigned u0 = __float_as_uint(f0); u0 = (u0 + 0x7FFFu + ((u0 >> 16) & 1u)) >> 16;
    unsigned u1 = __float_as_uint(f1); u1 = (u1 + 0x7FFFu + ((u1 >> 16) & 1u)) >> 16;
    return u0 | (u1 << 16);
}

// monotone uint32 transform: u < v  <=>  f < g
__device__ inline unsigned monokey(float f) {
    unsigned u = __float_as_uint(f);
    return u ^ ((unsigned)((int)u >> 31) | 0x80000000u);
}

// min over each 16-lane row via DPP (VALU-latency cross-lane, no DS pipe)
__device__ inline unsigned dppmin16(unsigned v) {
    unsigned t;
    t = (unsigned)__builtin_amdgcn_update_dpp((int)v, (int)v, 0xB1, 0xF, 0xF, false);  // quad [1,0,3,2]
    v = v < t ? v : t;
    t = (unsigned)__builtin_amdgcn_update_dpp((int)v, (int)v, 0x4E, 0xF, 0xF, false);  // quad [2,3,0,1]
    v = v < t ? v : t;
    t = (unsigned)__builtin_amdgcn_update_dpp((int)v, (int)v, 0x141, 0xF, 0xF, false); // row_half_mirror
    v = v < t ? v : t;
    t = (unsigned)__builtin_amdgcn_update_dpp((int)v, (int)v, 0x140, 0xF, 0xF, false); // row_mirror
    v = v < t ? v : t;
    return v;
}

// ---------------------------------------------------------------------------
// bitonic sort of 16 u64 keys, ascending (validated bit-exact in round 4)
// ---------------------------------------------------------------------------
__device__ inline void sort16_u64(unsigned long long key[16]) {
#pragma unroll
    for (int k = 2; k <= 16; k <<= 1) {
#pragma unroll
        for (int j = k >> 1; j > 0; j >>= 1) {
#pragma unroll
            for (int a = 0; a < 16; ++a) {
                int b = a ^ j;
                if (b > a) {
                    unsigned long long x = key[a], y = key[b];
                    bool lt = x < y;
                    unsigned long long mn = lt ? x : y, mx = lt ? y : x;
                    if ((a & k) == 0) { key[a] = mn; key[b] = mx; }
                    else              { key[a] = mx; key[b] = mn; }
                }
            }
        }
    }
}

// ---------------------------------------------------------------------------
// interleaved dual-row tournament: two independent selection chains issue in
// each other's stall shadows. hrow* = sorted u32 values slot-major
// (p*64+lane); perm* = original-slot nibbles of the sorted runs.
// ---------------------------------------------------------------------------
__device__ inline void dual_tourney20(
    unsigned* __restrict__ hrow0, unsigned long long perm0,
    unsigned* __restrict__ hrow1, unsigned long long perm1,
    int lane, int* __restrict__ outA, int* __restrict__ outB, int jadd)
{
    unsigned ptrA = 0, ptrB = 0;
    unsigned curA = hrow0[lane], nxtA = hrow0[64 + lane];
    unsigned curB = hrow1[lane], nxtB = hrow1[64 + lane];
    unsigned csA = (unsigned)(perm0 & 15ull), nsA = (unsigned)((perm0 >> 4) & 15ull);
    unsigned csB = (unsigned)(perm1 & 15ull), nsB = (unsigned)((perm1 >> 4) & 15ull);
    for (int t = 0; t < KNB; ++t) {
        unsigned rmA = dppmin16(curA);
        unsigned rmB = dppmin16(curB);
        unsigned a0 = (unsigned)__builtin_amdgcn_readlane((int)rmA, 0);
        unsigned b0 = (unsigned)__builtin_amdgcn_readlane((int)rmB, 0);
        unsigned a1 = (unsigned)__builtin_amdgcn_readlane((int)rmA, 16);
        unsigned b1 = (unsigned)__builtin_amdgcn_readlane((int)rmB, 16);
        unsigned a2 = (unsigned)__builtin_amdgcn_readlane((int)rmA, 32);
        unsigned b2 = (unsigned)__builtin_amdgcn_readlane((int)rmB, 32);
        unsigned a3 = (unsigned)__builtin_amdgcn_readlane((int)rmA, 48);
        unsigned b3 = (unsigned)__builtin_amdgcn_readlane((int)rmB, 48);
        unsigned gA = min(min(a0, a1), min(a2, a3));
        unsigned gB = min(min(b0, b1), min(b2, b3));
        unsigned long long ballA = __ballot(curA == gA);
        unsigned long long ballB = __ballot(curB == gB);
        int wlA = __ffsll(ballA) - 1;
        int wlB = __ffsll(ballB) - 1;
        int jA = (lane << 4) + (int)csA;
        int jB = (lane << 4) + (int)csB;
        int wjA = __builtin_amdgcn_readlane(jA, wlA);
        int wjB = __builtin_amdgcn_readlane(jB, wlB);
        if (lane == 0) { outA[t] = jadd + wjA; outB[t] = jadd + wjB; }
        if (lane == wlA) {
            curA = nxtA; csA = nsA;
            ptrA += 1u;
            unsigned p2 = ptrA + 1u;
            unsigned p2c = p2 < 15u ? p2 : 15u;
            nsA = (unsigned)((perm0 >> (4 * (int)p2c)) & 15ull);
            nxtA = (p2 < 16u) ? hrow0[p2 * 64 + lane] : 0xFFFFFFFFu;
        }
        if (lane == wlB) {
            curB = nxtB; csB = nsB;
            ptrB += 1u;
            unsigned p2 = ptrB + 1u;
            unsigned p2c = p2 < 15u ? p2 : 15u;
            nsB = (unsigned)((perm1 >> (4 * (int)p2c)) & 15ull);
            nxtB = (p2 < 16u) ? hrow1[p2 * 64 + lane] : 0xFFFFFFFFu;
        }
    }
}

// ---------------------------------------------------------------------------
__global__ void fail_kernel(float* out, int n) {
    int i = blockIdx.x * 256 + threadIdx.x;
    if (i < n) out[i] = -777.0f;
}

// ---------------------------------------------------------------------------
// phase1: fused knn3 (blocks 0..2047, dual-row waves) + prep_uv1 (2048..6143)
// + prep_w (rest). knn3 heap = 32 KB u32.
// ---------------------------------------------------------------------------
__global__ __launch_bounds__(256) void phase1_kernel(
    const float* __restrict__ pos, const float* __restrict__ W1a, const float* __restrict__ b1a,
    const float* __restrict__ W2,
    const float* __restrict__ Wm1, const float* __restrict__ Wm2, const float* __restrict__ Wm3,
    const float* __restrict__ Wl, const float* __restrict__ W1b, const float* __restrict__ W1c,
    int* __restrict__ idx, float* __restrict__ u1, float* __restrict__ v1,
    float* __restrict__ Wcat, float* __restrict__ Wm1T, float* __restrict__ Wm2T, float* __restrict__ Wm3T,
    ushortT* __restrict__ Wlb, _Float16* __restrict__ Wc1f)
{
    __shared__ unsigned heap[4][2][1024];   // 32 KB
    const int bid = blockIdx.x;
    const int tid = threadIdx.x;
    if (bid < 2048) {
        const int w = tid >> 6, lane = tid & 63;
        const int b = bid >> 7;
        const int ibase = ((bid & 127) << 3) + (w << 1);   // rows ibase, ibase+1
        const float* pb = pos + (size_t)b * NP * 3;
        float cbuf[48];
        {
            const float4* src = (const float4*)(pb + lane * 48);
#pragma unroll
            for (int q = 0; q < 12; ++q) *(float4*)&cbuf[q * 4] = src[q];
        }
        unsigned* hrow0 = &heap[w][0][0];
        unsigned* hrow1 = &heap[w][1][0];
        unsigned long long perm0 = 0, perm1 = 0;
        {
            const int i = ibase;
            const float xi = pb[3 * i], yi = pb[3 * i + 1], zi = pb[3 * i + 2];
            const float sqi = xi * xi + yi * yi + zi * zi;
            unsigned long long key[16];
#pragma unroll
            for (int s = 0; s < 16; ++s) {
                float x = cbuf[3 * s], y = cbuf[3 * s + 1], z = cbuf[3 * s + 2];
                float d = sqi + (x * x + y * y + z * z) - 2.0f * (xi * x + yi * y + zi * z);
                int j = (lane << 4) + s;
                if (j == i) d += 1e10f;
                key[s] = ((unsigned long long)monokey(d) << 32) | (unsigned)j;
            }
            sort16_u64(key);
#pragma unroll
            for (int p = 0; p < 16; ++p) {
                hrow0[p * 64 + lane] = (unsigned)(key[p] >> 32);
                perm0 |= (unsigned long long)((unsigned)key[p] & 15u) << (4 * p);
            }
        }
        {
            const int i = ibase + 1;
            const float xi = pb[3 * i], yi = pb[3 * i + 1], zi = pb[3 * i + 2];
            const float sqi = xi * xi + yi * yi + zi * zi;
            unsigned long long key[16];
#pragma unroll
            for (int s = 0; s < 16; ++s) {
                float x = cbuf[3 * s], y = cbuf[3 * s + 1], z = cbuf[3 * s + 2];
                float d = sqi + (x * x + y * y + z * z) - 2.0f * (xi * x + yi * y + zi * z);
                int j = (lane << 4) + s;
                if (j == i) d += 1e10f;
                key[s] = ((unsigned long long)monokey(d) << 32) | (unsigned)j;
            }
            sort16_u64(key);
#pragma unroll
            for (int p = 0; p < 16; ++p) {
                hrow1[p * 64 + lane] = (unsigned)(key[p] >> 32);
                perm1 |= (unsigned long long)((unsigned)key[p] & 15u) << (4 * p);
            }
        }
        dual_tourney20(hrow0, perm0, hrow1, perm1, lane,
                       idx + (size_t)(b * NP + ibase) * KNB,
                       idx + (size_t)(b * NP + ibase + 1) * KNB, b * NP);
        return;
    }
    if (bid < 6144) {
        int id = (bid - 2048) * 256 + tid;  // 16384*64
        int i = id >> 6, c = id & 63;
        float x = pos[3 * i], y = pos[3 * i + 1], z = pos[3 * i + 2];
        float wu0 = W1a[3 * 64 + c], wu1 = W1a[4 * 64 + c], wu2 = W1a[5 * 64 + c];
        float wv0 = W1a[0 * 64 + c] - wu0, wv1 = W1a[1 * 64 + c] - wu1, wv2 = W1a[2 * 64 + c] - wu2;
        u1[id] = x * wu0 + y * wu1 + z * wu2;
        v1[id] = b1a[c] + x * wv0 + y * wv1 + z * wv2;
        return;
    }
    int id = (bid - 6144) * 256 + tid;
    if (id < 64 * 256) {
        int c = id >> 8, n = id & 255;
        float wb = W2[(64 + c) * 128 + (n & 127)];
        Wcat[id] = (n < 128) ? wb : (W2[c * 128 + (n - 128)] - wb);
        return;
    }
    id -= 64 * 256;
    if (id < 512 * 1024) { int j = id >> 10, c = id & 1023; Wm1T[id] = Wm1[c * 512 + j]; return; }
    id -= 512 * 1024;
    if (id < 256 * 512)  { int j = id >> 9,  c = id & 511;  Wm2T[id] = Wm2[c * 256 + j]; return; }
    id -= 256 * 512;
    if (id < 40 * 256)   { int j = id >> 8,  c = id & 255;  Wm3T[id] = Wm3[c * 40 + j];  return; }
    id -= 40 * 256;
    if (id < 8 * 6 * 8 * 64 * 8) {
        int j = id & 7;
        int t = id >> 3;
        int lane = t & 63; t >>= 6;
        int f = t & 7; t >>= 3;
        int s = t % 6, nt = t / 6;
        int k = s * 32 + (lane >> 4) * 8 + j;
        int n = nt * 128 + f * 16 + (lane & 15);
        unsigned u = __float_as_uint(Wl[(size_t)k * 1024 + n]);
        u = (u + 0x7FFFu + ((u >> 16) & 1u)) >> 16;
        Wlb[id] = (ushortT)u;
        return;
    }
    id -= 8 * 6 * 8 * 64 * 8;
    if (id < 16384) {
        int mat = id >> 13;
        int rem = id & 8191;
        int part = rem >> 12;
        int t = rem & 4095;
        int frag = t >> 9;
        int r = t & 511;
        int lane = r >> 3, j = r & 7;
        int kf = frag >> 2, nf = frag & 3;
        int k = kf * 32 + (lane >> 4) * 8 + j;
        int n = nf * 16 + (lane & 15);
        float w = (mat ? W1c : W1b)[k * 64 + n];
        _Float16 hi = (_Float16)w;
        Wc1f[id] = part ? (_Float16)(w - (float)hi) : hi;
        return;
    }
}

// ---------------------------------------------------------------------------
// conv1 via split-fp16 MFMA: 1 wave = 16 points, one edge per pass (20 passes).
// ---------------------------------------------------------------------------
__global__ __launch_bounds__(64, 1) void conv1_mfma_kernel(
    const int* __restrict__ idx, const float* __restrict__ u1, const float* __restrict__ v1,
    const _Float16* __restrict__ Wf, const float* __restrict__ b1b, const float* __restrict__ b1c,
    float* __restrict__ x1)
{
    __shared__ int idx_s[16 * 20];
    __shared__ __align__(16) float tr[16 * 68];    // h2 transpose buffer
    __shared__ __align__(16) float xout[16 * 68];  // final x1 staging
    const int lane = threadIdx.x;
    const int row = lane & 15, ks = lane >> 4;
    const int pbase = blockIdx.x * 16;

    for (int t = lane; t < 320; t += 64) idx_s[t] = idx[(size_t)pbase * 20 + t];

    const f16x8* Wp = (const f16x8*)Wf;
    f16x8 wbh[2][4], wbl[2][4], wch[2][4], wcl[2][4];
#pragma unroll
    for (int kf = 0; kf < 2; ++kf)
#pragma unroll
        for (int nf = 0; nf < 4; ++nf) {
            int f = kf * 4 + nf;
            wbh[kf][nf] = Wp[(0 * 8 + f) * 64 + lane];
            wbl[kf][nf] = Wp[(1 * 8 + f) * 64 + lane];
            wch[kf][nf] = Wp[(2 * 8 + f) * 64 + lane];
            wcl[kf][nf] = Wp[(3 * 8 + f) * 64 + lane];
        }
    float bb[4], bc[4];
#pragma unroll
    for (int nf = 0; nf < 4; ++nf) { bb[nf] = b1b[nf * 16 + row]; bc[nf] = b1c[nf * 16 + row]; }

    const int P = pbase + row;
    float4 v1f[4];
    {
        const float4* v4a = (const float4*)(v1 + (size_t)P * 64 + ks * 8);
        v1f[0] = v4a[0]; v1f[1] = v4a[1];
        const float4* v4b = (const float4*)(v1 + (size_t)P * 64 + 32 + ks * 8);
        v1f[2] = v4b[0]; v1f[3] = v4b[1];
    }
    f32x4 xmax[4];
#pragma unroll
    for (int nf = 0; nf < 4; ++nf) xmax[nf] = (f32x4)(-3.0e38f);

    int jn = idx_s[row * 20];
    float4 un[4];
    {
        const float4* up = (const float4*)(u1 + (size_t)jn * 64 + ks * 8);
        un[0] = up[0]; un[1] = up[1];
        const float4* up2 = (const float4*)(u1 + (size_t)jn * 64 + 32 + ks * 8);
        un[2] = up2[0]; un[3] = up2[1];
    }
    for (int e = 0; e < 20; ++e) {
        float4 uc[4] = {un[0], un[1], un[2], un[3]};
        if (e < 19) {
            jn = idx_s[row * 20 + e + 1];
            const float4* up = (const float4*)(u1 + (size_t)jn * 64 + ks * 8);
            un[0] = up[0]; un[1] = up[1];
            const float4* up2 = (const float4*)(u1 + (size_t)jn * 64 + 32 + ks * 8);
            un[2] = up2[0]; un[3] = up2[1];
        }
        f32x4 c2[4];
#pragma unroll
        for (int nf = 0; nf < 4; ++nf) c2[nf] = (f32x4)(bb[nf]);
#pragma unroll
        for (int kf = 0; kf < 2; ++kf) {
            const float* uu = (const float*)&uc[kf * 2];
            const float* vv = (const float*)&v1f[kf * 2];
            f16x8 ah, al;
#pragma unroll
            for (int q = 0; q < 8; ++q) {
                float h = fmaxf(uu[q] + vv[q], 0.f);
                _Float16 hi = (_Float16)h;
                ah[q] = hi;
                al[q] = (_Float16)(h - (float)hi);
            }
#pragma unroll
            for (int nf = 0; nf < 4; ++nf) {
                c2[nf] = __builtin_amdgcn_mfma_f32_16x16x32_f16(ah, wbh[kf][nf], c2[nf], 0, 0, 0);
                c2[nf] = __builtin_amdgcn_mfma_f32_16x16x32_f16(ah, wbl[kf][nf], c2[nf], 0, 0, 0);
                c2[nf] = __builtin_amdgcn_mfma_f32_16x16x32_f16(al, wbh[kf][nf], c2[nf], 0, 0, 0);
            }
        }
#pragma unroll
        for (int nf = 0; nf < 4; ++nf)
#pragma unroll
            for (int r = 0; r < 4; ++r)
                tr[(ks * 4 + r) * 68 + nf * 16 + row] = fmaxf(c2[nf][r], 0.f);
        __builtin_amdgcn_sched_barrier(0);
        f32x4 c3[4];
#pragma unroll
        for (int nf = 0; nf < 4; ++nf) c3[nf] = (f32x4)0.0f;
#pragma unroll
        for (int kf = 0; kf < 2; ++kf) {
            float hbuf[8];
            *(float4*)&hbuf[0] = *(const float4*)&tr[row * 68 + kf * 32 + ks * 8];
            *(float4*)&hbuf[4] = *(const float4*)&tr[row * 68 + kf * 32 + ks * 8 + 4];
            f16x8 ah, al;
#pragma unroll
            for (int q = 0; q < 8; ++q) {
                _Float16 hi = (_Float16)hbuf[q];
                ah[q] = hi;
                al[q] = (_Float16)(hbuf[q] - (float)hi);
            }
#pragma unroll
            for (int nf = 0; nf < 4; ++nf) {
                c3[nf] = __builtin_amdgcn_mfma_f32_16x16x32_f16(ah, wch[kf][nf], c3[nf], 0, 0, 0);
                c3[nf] = __builtin_amdgcn_mfma_f32_16x16x32_f16(ah, wcl[kf][nf], c3[nf], 0, 0, 0);
                c3[nf] = __builtin_amdgcn_mfma_f32_16x16x32_f16(al, wch[kf][nf], c3[nf], 0, 0, 0);
            }
        }
        __builtin_amdgcn_sched_barrier(0);
#pragma unroll
        for (int nf = 0; nf < 4; ++nf) {
            xmax[nf][0] = fmaxf(xmax[nf][0], c3[nf][0]);
            xmax[nf][1] = fmaxf(xmax[nf][1], c3[nf][1]);
            xmax[nf][2] = fmaxf(xmax[nf][2], c3[nf][2]);
            xmax[nf][3] = fmaxf(xmax[nf][3], c3[nf][3]);
        }
    }
#pragma unroll
    for (int nf = 0; nf < 4; ++nf)
#pragma unroll
        for (int r = 0; r < 4; ++r)
            xout[(ks * 4 + r) * 68 + nf * 16 + row] = xmax[nf][r] + bc[nf];
    __builtin_amdgcn_sched_barrier(0);
    {
        const int r2 = lane >> 2, c0 = (lane & 3) * 16;
#pragma unroll
        for (int q = 0; q < 4; ++q) {
            float4 v = *(const float4*)&xout[r2 * 68 + c0 + q * 4];
            *(float4*)(x1 + (size_t)(pbase + r2) * 64 + c0 + q * 4) = v;
        }
    }
}

// ---------------------------------------------------------------------------
// sq norms of x1 rows + Afrag bf16 pack (lin1max) + Xf split-fp16 frags (dist2sel)
// ---------------------------------------------------------------------------
__global__ __launch_bounds__(256) void sqnorm_kernel(
    const float* __restrict__ x1, float* __restrict__ sq,
    ushortT* __restrict__ Afrag, _Float16* __restrict__ Xf)
{
    int i = blockIdx.x * 256 + threadIdx.x;  // 16384
    const float4* r = (const float4*)(x1 + (size_t)i * 64);
    float c[64];
    float s = 0.f;
#pragma unroll
    for (int q = 0; q < 16; ++q) {
        float4 a = r[q];
        c[4 * q] = a.x; c[4 * q + 1] = a.y; c[4 * q + 2] = a.z; c[4 * q + 3] = a.w;
        s += a.x * a.x + a.y * a.y + a.z * a.z + a.w * a.w;
    }
    sq[i] = s;
    const size_t t = i >> 4;
#pragma unroll
    for (int cb = 0; cb < 8; ++cb) {
        uint4 pk;
        pk.x = f2bf_pair(c[8 * cb + 0], c[8 * cb + 1]);
        pk.y = f2bf_pair(c[8 * cb + 2], c[8 * cb + 3]);
        pk.z = f2bf_pair(c[8 * cb + 4], c[8 * cb + 5]);
        pk.w = f2bf_pair(c[8 * cb + 6], c[8 * cb + 7]);
        size_t af = (t * 6 + (cb >> 2)) * 512 + (size_t)((cb & 3) * 16 + (i & 15)) * 8;
        *(uint4*)(Afrag + af) = pk;
        int kf = cb >> 2;
        int lanef = ((cb & 3) << 4) + (i & 15);
        __align__(16) _Float16 hbuf[8];
        __align__(16) _Float16 lbuf[8];
#pragma unroll
        for (int q2 = 0; q2 < 8; ++q2) {
            float v = c[cb * 8 + q2];
            _Float16 hi = (_Float16)v;
            hbuf[q2] = hi;
            lbuf[q2] = (_Float16)(v - (float)hi);
        }
        *(uint4*)(Xf + ((t * 2 + kf) * 2 + 0) * 512 + (size_t)lanef * 8) = *(uint4*)hbuf;
        *(uint4*)(Xf + ((t * 2 + kf) * 2 + 1) * 512 + (size_t)lanef * 8) = *(uint4*)lbuf;
    }
}

// ---------------------------------------------------------------------------
// dist2sel v6: 8 waves/block (512 thr); wave owns 2 rows; sorts sequential,
// tournaments INTERLEAVED. LDS 64 KB stride 1024; heap slot-major per row.
// ---------------------------------------------------------------------------
__global__ __launch_bounds__(512, 2) void dist2sel_kernel(
    const _Float16* __restrict__ Xf, const float* __restrict__ sq, int* __restrict__ idx)
{
    __shared__ unsigned kls[16 * 1024];   // 64 KB
    const int tid = threadIdx.x;
    const int w = tid >> 6, lane = tid & 63;   // w in 0..7
    const int b = blockIdx.x >> 6;
    const int rowtile = blockIdx.x & 63;
    const int c15 = lane & 15;
    const int rbase = (lane >> 4) * 4;

    const f16x8* Xv = (const f16x8*)Xf;
    const int tA = b * 64 + rowtile;
    f16x8 ah[2], al[2];
#pragma unroll
    for (int kf = 0; kf < 2; ++kf) {
        ah[kf] = Xv[((size_t)(tA * 2 + kf) * 2 + 0) * 64 + lane];
        al[kf] = Xv[((size_t)(tA * 2 + kf) * 2 + 1) * 64 + lane];
    }
    const float* sqb = sq + (size_t)b * NP;
    float sqi[4];
#pragma unroll
    for (int rr = 0; rr < 4; ++rr)
        sqi[rr] = sqb[rowtile * 16 + rbase + rr];

    for (int q = 0; q < 8; ++q) {
        const int ct = w * 8 + q;
        const int tB = b * 64 + ct;
        f16x8 bh0 = Xv[((size_t)(tB * 2 + 0) * 2 + 0) * 64 + lane];
        f16x8 bl0 = Xv[((size_t)(tB * 2 + 0) * 2 + 1) * 64 + lane];
        f16x8 bh1 = Xv[((size_t)(tB * 2 + 1) * 2 + 0) * 64 + lane];
        f16x8 bl1 = Xv[((size_t)(tB * 2 + 1) * 2 + 1) * 64 + lane];
        const int col = ct * 16 + c15;
        const float sqj = sqb[col];
        f32x4 acc = (f32x4)0.0f;
        acc = __builtin_amdgcn_mfma_f32_16x16x32_f16(ah[0], bh0, acc, 0, 0, 0);
        acc = __builtin_amdgcn_mfma_f32_16x16x32_f16(ah[0], bl0, acc, 0, 0, 0);
        acc = __builtin_amdgcn_mfma_f32_16x16x32_f16(al[0], bh0, acc, 0, 0, 0);
        acc = __builtin_amdgcn_mfma_f32_16x16x32_f16(ah[1], bh1, acc, 0, 0, 0);
        acc = __builtin_amdgcn_mfma_f32_16x16x32_f16(ah[1], bl1, acc, 0, 0, 0);
        acc = __builtin_amdgcn_mfma_f32_16x16x32_f16(al[1], bh1, acc, 0, 0, 0);
        const int pc = col ^ ((col >> 6) & 15);   // bank swizzle (bijective per 64-col block)
#pragma unroll
        for (int rr = 0; rr < 4; ++rr) {
            float d = sqi[rr] + sqj - 2.0f * acc[rr];
            if (rowtile * 16 + rbase + rr == col) d += 1e10f;
            kls[(rbase + rr) * 1024 + pc] = monokey(d);
        }
    }
    __syncthreads();

    const int gb = b * NP;
    const int r0 = 2 * w, r1 = 2 * w + 1;
    unsigned* hrow0 = &kls[r0 * 1024];
    unsigned* hrow1 = &kls[r1 * 1024];
    unsigned long long perm0 = 0, perm1 = 0;
    {
        unsigned long long key[16];
#pragma unroll
        for (int s = 0; s < 16; ++s) {
            int col = (lane << 4) + s;
            int pc = col ^ ((col >> 6) & 15);
            key[s] = ((unsigned long long)kls[r0 * 1024 + pc] << 32) | (unsigned)col;
        }
        sort16_u64(key);
#pragma unroll
        for (int p = 0; p < 16; ++p) {
            hrow0[p * 64 + lane] = (unsigned)(key[p] >> 32);
            perm0 |= (unsigned long long)((unsigned)key[p] & 15u) << (4 * p);
        }
    }
    {
        unsigned long long key[16];
#pragma unroll
        for (int s = 0; s < 16; ++s) {
            int col = (lane << 4) + s;
            int pc = col ^ ((col >> 6) & 15);
            key[s] = ((unsigned long long)kls[r1 * 1024 + pc] << 32) | (unsigned)col;
        }
        sort16_u64(key);
#pragma unroll
        for (int p = 0; p < 16; ++p) {
            hrow1[p * 64 + lane] = (unsigned)(key[p] >> 32);
            perm1 |= (unsigned long long)((unsigned)key[p] & 15u) << (4 * p);
        }
    }
    dual_tourney20(hrow0, perm0, hrow1, perm1, lane,
                   idx + (size_t)(gb + rowtile * 16 + r0) * KNB,
                   idx + (size_t)(gb + rowtile * 16 + r1) * KNB, gb);
}

// ---------------------------------------------------------------------------
// u2/v2 GEMM: [16384 x 64] @ Wcat[64 x 256] -> u2 (n<128), v2 (+b2, n>=128)
// ---------------------------------------------------------------------------
__global__ __launch_bounds__(256) void u2v2_kernel(
    const float* __restrict__ x1, const float* __restrict__ Wcat, const float* __restrict__ b2,
    float* __restrict__ u2, float* __restrict__ v2)
{
    __shared__ float aT[32][132];
    __shared__ float bW[32][132];
    const int tid = threadIdx.x;
    const int mt = blockIdx.x >> 1, nt = blockIdx.x & 1;
    const int m0 = mt << 7, n0 = nt << 7;
    const int ti = tid >> 4, tj = tid & 15;
    float acc[8][8];
#pragma unroll
    for (int a = 0; a < 8; ++a)
#pragma unroll
        for (int q = 0; q < 8; ++q) acc[a][q] = 0.f;
    for (int ct = 0; ct < 2; ++ct) {
        __syncthreads();
#pragma unroll
        for (int rep = 0; rep < 4; ++rep) {
            int f = tid + (rep << 8);
            { int r = f >> 3, q = f & 7;
              float4 v = *(const float4*)(x1 + (size_t)(m0 + r) * 64 + ct * 32 + q * 4);
              aT[4 * q + 0][r] = v.x; aT[4 * q + 1][r] = v.y; aT[4 * q + 2][r] = v.z; aT[4 * q + 3][r] = v.w; }
            { int cc = f >> 5, q = f & 31;
              *(float4*)&bW[cc][4 * q] = *(const float4*)(Wcat + (size_t)(ct * 32 + cc) * 256 + n0 + q * 4); }
        }
        __syncthreads();
#pragma unroll 4
        for (int c = 0; c < 32; ++c) {
            float af[8], bf[8];
            *(float4*)&af[0] = *(const float4*)&aT[c][ti * 8];
            *(float4*)&af[4] = *(const float4*)&aT[c][ti * 8 + 4];
            *(float4*)&bf[0] = *(const float4*)&bW[c][tj * 8];
            *(float4*)&bf[4] = *(const float4*)&bW[c][tj * 8 + 4];
#pragma unroll
            for (int a = 0; a < 8; ++a)
#pragma unroll
                for (int q = 0; q < 8; ++q) acc[a][q] = fmaf(af[a], bf[q], acc[a][q]);
        }
    }
#pragma unroll
    for (int a = 0; a < 8; ++a) {
        int m = m0 + ti * 8 + a;
        if (n0 < 128) {
            float outv[8];
#pragma unroll
            for (int q = 0; q < 8; ++q) outv[q] = acc[a][q];
            *(float4*)(u2 + (size_t)m * 128 + n0 + tj * 8)     = *(float4*)&outv[0];
            *(float4*)(u2 + (size_t)m * 128 + n0 + tj * 8 + 4) = *(float4*)&outv[4];
        } else {
            float outv[8];
#pragma unroll
            for (int q = 0; q < 8; ++q) outv[q] = acc[a][q] + b2[n0 - 128 + tj * 8 + q];
            *(float4*)(v2 + (size_t)m * 128 + (n0 - 128) + tj * 8)     = *(float4*)&outv[0];
            *(float4*)(v2 + (size_t)m * 128 + (n0 - 128) + tj * 8 + 4) = *(float4*)&outv[4];
        }
    }
}

// ---------------------------------------------------------------------------
// conv2 gather-max -> Afrag k=64..191 (bf16 fragment layout), x2 never stored
// ---------------------------------------------------------------------------
__global__ __launch_bounds__(256) void gatherfrag_kernel(
    const int* __restrict__ idx, const float* __restrict__ u2,
    const float* __restrict__ v2, ushortT* __restrict__ Afrag)
{
    const int tid = threadIdx.x;
    const int i = blockIdx.x * 16 + (tid >> 4);
    const int cb = tid & 15;
    const int* ib = idx + (size_t)i * KNB;
    float m[8];
#pragma unroll
    for (int d = 0; d < 8; ++d) m[d] = -3e38f;
    for (int e = 0; e < KNB; ++e) {
        int j = ib[e];
        const float4* p = (const float4*)(u2 + (size_t)j * 128 + cb * 8);
        float4 a = p[0], b = p[1];
        m[0] = fmaxf(m[0], a.x); m[1] = fmaxf(m[1], a.y); m[2] = fmaxf(m[2], a.z); m[3] = fmaxf(m[3], a.w);
        m[4] = fmaxf(m[4], b.x); m[5] = fmaxf(m[5], b.y); m[6] = fmaxf(m[6], b.z); m[7] = fmaxf(m[7], b.w);
    }
    const float4* vp = (const float4*)(v2 + (size_t)i * 128 + cb * 8);
    float4 va = vp[0], vb = vp[1];
    m[0] += va.x; m[1] += va.y; m[2] += va.z; m[3] += va.w;
    m[4] += vb.x; m[5] += vb.y; m[6] += vb.z; m[7] += vb.w;
    uint4 pk;
    pk.x = f2bf_pair(m[0], m[1]);
    pk.y = f2bf_pair(m[2], m[3]);
    pk.z = f2bf_pair(m[4], m[5]);
    pk.w = f2bf_pair(m[6], m[7]);
    size_t af = ((size_t)(i >> 4) * 6 + 2 + (cb >> 2)) * 512 + (size_t)((cb & 3) * 16 + (i & 15)) * 8;
    *(uint4*)(Afrag + af) = pk;
}

// ---------------------------------------------------------------------------
// lin1 + global max pool via bf16 MFMA.
// ---------------------------------------------------------------------------
__global__ __launch_bounds__(256) void lin1max_mfma_kernel(
    const ushortT* __restrict__ Afrag, const ushortT* __restrict__ Wlb, float* __restrict__ gp)
{
    __shared__ float red[4][128];
    const int tid = threadIdx.x;
    const int w = tid >> 6, lane = tid & 63;
    const int nt = blockIdx.x & 7;
    const int rt = (blockIdx.x >> 3) & 7;
    const int b  = blockIdx.x >> 6;
    const int rt16 = ((b << 3) + rt) * 8 + (w << 1);
    const bf16x8* Ap = (const bf16x8*)Afrag;
    const bf16x8* Bp = (const bf16x8*)Wlb;
    f32x4 acc[2][8];
#pragma unroll
    for (int mm = 0; mm < 2; ++mm)
#pragma unroll
        for (int f = 0; f < 8; ++f) acc[mm][f] = (f32x4)0.0f;
#pragma unroll
    for (int s = 0; s < 6; ++s) {
        bf16x8 a0 = Ap[((rt16    ) * 6 + s) * 64 + lane];
        bf16x8 a1 = Ap[((rt16 + 1) * 6 + s) * 64 + lane];
#pragma unroll
        for (int f = 0; f < 8; ++f) {
            bf16x8 bb = Bp[(((nt * 6 + s) << 3) + f) * 64 + lane];
            acc[0][f] = __builtin_amdgcn_mfma_f32_16x16x32_bf16(a0, bb, acc[0][f], 0, 0, 0);
            acc[1][f] = __builtin_amdgcn_mfma_f32_16x16x32_bf16(a1, bb, acc[1][f], 0, 0, 0);
        }
    }
#pragma unroll
    for (int f = 0; f < 8; ++f) {
        float m = acc[0][f][0];
        m = fmaxf(m, acc[0][f][1]); m = fmaxf(m, acc[0][f][2]); m = fmaxf(m, acc[0][f][3]);
        m = fmaxf(m, acc[1][f][0]); m = fmaxf(m, acc[1][f][1]);
        m = fmaxf(m, acc[1][f][2]); m = fmaxf(m, acc[1][f][3]);
        m = fmaxf(m, __shfl_xor(m, 16, 64));
        m = fmaxf(m, __shfl_xor(m, 32, 64));
        if (lane < 16) red[w][f * 16 + lane] = m;
    }
    __syncthreads();
    if (tid < 128) {
        float m = fmaxf(fmaxf(red[0][tid], red[1][tid]), fmaxf(red[2][tid], red[3][tid]));
        gp[((size_t)rt * NB + b) * 1024 + nt * 128 + tid] = m;
    }
}

// ---------------------------------------------------------------------------
// head stage 0: gs[b][c] = max over 8 gp parts + bl[c]   (16x1024)
// ---------------------------------------------------------------------------
__global__ __launch_bounds__(256) void gmax_kernel(
    const float* __restrict__ gp, const float* __restrict__ bl, float* __restrict__ gs)
{
    int id = blockIdx.x * 256 + threadIdx.x;   // 16384
    int b = id >> 10, c = id & 1023;
    float m = gp[(size_t)b * 1024 + c];
#pragma unroll
    for (int part = 1; part < 8; ++part)
        m = fmaxf(m, gp[((size_t)part * NB + b) * 1024 + c]);
    gs[(size_t)b * 1024 + c] = m + bl[c];
}

// ---------------------------------------------------------------------------
// head stage 1: h1[b][j] = relu(gs[b] . Wm1T[j] + bm1[j]); one block per j.
// ---------------------------------------------------------------------------
__global__ __launch_bounds__(256) void head1_kernel(
    const float* __restrict__ gs, const float* __restrict__ Wm1T, const float* __restrict__ bm1,
    float* __restrict__ h1)
{
    __shared__ float red[16][17];
    const int j = blockIdx.x;                  // 0..511
    const int t = threadIdx.x;
    const int b = t >> 4, seg = t & 15;
    const float4* wr = (const float4*)(Wm1T + (size_t)j * 1024 + seg * 64);
    const float4* gr = (const float4*)(gs + (size_t)b * 1024 + seg * 64);
    float acc = 0.f;
#pragma unroll
    for (int q = 0; q < 16; ++q) {
        float4 w = wr[q], g = gr[q];
        acc = fmaf(w.x, g.x, acc); acc = fmaf(w.y, g.y, acc);
        acc = fmaf(w.z, g.z, acc); acc = fmaf(w.w, g.w, acc);
    }
    red[b][seg] = acc;
    __syncthreads();
    if (t < 16) {
        float s = 0.f;
#pragma unroll
        for (int k = 0; k < 16; ++k) s += red[t][k];
        h1[(size_t)t * 512 + j] = fmaxf(s + bm1[j], 0.f);
    }
}

// ---------------------------------------------------------------------------
// head stage 2: h2[b][j] = relu(h1[b] . Wm2T[j] + bm2[j]); one block per j.
// ---------------------------------------------------------------------------
__global__ __launch_bounds__(256) void head2_kernel(
    const float* __restrict__ h1, const float* __restrict__ Wm2T, const float* __restrict__ bm2,
    float* __restrict__ h2)
{
    __shared__ float red[16][17];
    const int j = blockIdx.x;                  // 0..255
    const int t = threadIdx.x;
    const int b = t >> 4, seg = t & 15;
    const float4* wr = (const float4*)(Wm2T + (size_t)j * 512 + seg * 32);
    const float4* hr = (const float4*)(h1 + (size_t)b * 512 + seg * 32);
    float acc = 0.f;
#pragma unroll
    for (int q = 0; q < 8; ++q) {
        float4 w = wr[q], g = hr[q];
        acc = fmaf(w.x, g.x, acc); acc = fmaf(w.y, g.y, acc);
        acc = fmaf(w.z, g.z, acc); acc = fmaf(w.w, g.w, acc);
    }
    red[b][seg] = acc;
    __syncthreads();
    if (t < 16) {
        float s = 0.f;
#pragma unroll
        for (int k = 0; k < 16; ++k) s += red[t][k];
        h2[(size_t)t * 256 + j] = fmaxf(s + bm2[j], 0.f);
    }
}

// ---------------------------------------------------------------------------
// head stage 3: logits + log_softmax; one block per batch.
// ---------------------------------------------------------------------------
__global__ __launch_bounds__(256) void head3_kernel(
    const float* __restrict__ h2, const float* __restrict__ Wm3T, const float* __restrict__ bm3,
    float* __restrict__ out)
{
    __shared__ float lg[64];
    const int tid = threadIdx.x;
    const int b = blockIdx.x;
    if (tid < 40) {
        float acc = bm3[tid];
        const float4* wr = (const float4*)(Wm3T + (size_t)tid * 256);
        const float4* hr = (const float4*)(h2 + (size_t)b * 256);
#pragma unroll
        for (int c4 = 0; c4 < 64; ++c4) {
            float4 w = wr[c4];
            float4 g4 = hr[c4];
            acc = fmaf(w.x, g4.x, acc); acc = fmaf(w.y, g4.y, acc);
            acc = fmaf(w.z, g4.z, acc); acc = fmaf(w.w, g4.w, acc);
        }
        lg[tid] = acc;
    }
    __syncthreads();
    if (tid < 64) {
        float v = (tid < 40) ? lg[tid] : -3e38f;
        float m = v;
        for (int off = 32; off; off >>= 1) m = fmaxf(m, __shfl_xor(m, off, 64));
        float ex = (tid < 40) ? expf(v - m) : 0.f;
        float s = ex;
        for (int off = 32; off; off >>= 1) s += __shfl_xor(s, off, 64);
        if (tid < 40) out[b * 40 + tid] = v - m - logf(s);
    }
}

// ---------------------------------------------------------------------------
extern "C" void kernel_launch(void* const* d_in, const int* in_sizes, int n_in,
                              void* d_out, int out_size, void* d_ws, size_t ws_size,
                              hipStream_t stream)
{
    const float* pos = (const float*)d_in[0];
    const float* W1a = (const float*)d_in[1];
    const float* b1a = (const float*)d_in[2];
    const float* W1b = (const float*)d_in[3];
    const float* b1b = (const float*)d_in[4];
    const float* W1c = (const float*)d_in[5];
    const float* b1c = (const float*)d_in[6];
    const float* W2  = (const float*)d_in[7];
    const float* b2  = (const float*)d_in[8];
    const float* Wl  = (const float*)d_in[9];
    const float* bl  = (const float*)d_in[10];
    const float* Wm1 = (const float*)d_in[11];
    const float* bm1 = (const float*)d_in[12];
    const float* Wm2 = (const float*)d_in[13];
    const float* bm2 = (const float*)d_in[14];
    const float* Wm3 = (const float*)d_in[15];
    const float* bm3 = (const float*)d_in[16];
    float* out = (float*)d_out;

    char* ws = (char*)d_ws;
    const size_t MB = 1024 * 1024;
    size_t off = 0;
    auto alloc = [&](size_t bytes) { size_t o = off; off += (bytes + 255) & ~(size_t)255; return o; };
    size_t u2_off  = alloc(8 * MB);          // u1 (4MB) then u2 (8MB)
    size_t v2_off  = alloc(8 * MB);          // v1 (4MB) then v2 (8MB)
    size_t x1_off  = alloc(4 * MB);
    size_t idx_off = alloc((size_t)NPT * KNB * 4);
    size_t sq_off  = alloc((size_t)NPT * 4);
    size_t gp_off  = alloc((size_t)8 * NB * 1024 * 4);
    size_t gs_off  = alloc((size_t)NB * 1024 * 4);
    size_t h1_off  = alloc((size_t)NB * 512 * 4);
    size_t h2_off  = alloc((size_t)NB * 256 * 4);
    size_t wc_off  = alloc(64 * 256 * 4);
    size_t w1t_off = alloc(512 * 1024 * 4);
    size_t w2t_off = alloc(256 * 512 * 4);
    size_t w3t_off = alloc(40 * 256 * 4);
    size_t af_off  = alloc((size_t)(NPT / 16) * 6 * 512 * 2);  // 6 MB bf16 A-fragments
    size_t wlb_off = alloc((size_t)8 * 6 * 8 * 512 * 2);       // 384 KB bf16 Wl fragments
    size_t wcf_off = alloc((size_t)16384 * 2);                 // 32 KB split-fp16 conv1 W frags
    size_t xf_off  = alloc((size_t)(NPT / 16) * 2 * 2 * 512 * 2); // 4 MB split-fp16 x1 frags
    if (ws_size < off) { fail_kernel<<<3, 256, 0, stream>>>(out, out_size); return; }

    float* u1    = (float*)(ws + u2_off);
    float* v1    = (float*)(ws + v2_off);
    float* u2    = (float*)(ws + u2_off);
    float* v2    = (float*)(ws + v2_off);
    float* x1    = (float*)(ws + x1_off);
    int*   idx   = (int*)(ws + idx_off);
    float* sq    = (float*)(ws + sq_off);
    float* gp    = (float*)(ws + gp_off);
    float* gs    = (float*)(ws + gs_off);
    float* h1    = (float*)(ws + h1_off);
    float* h2    = (float*)(ws + h2_off);
    float* Wcat  = (float*)(ws + wc_off);
    float* Wm1T  = (float*)(ws + w1t_off);
    float* Wm2T  = (float*)(ws + w2t_off);
    float* Wm3T  = (float*)(ws + w3t_off);
    ushortT* Afrag = (ushortT*)(ws + af_off);
    ushortT* Wlb   = (ushortT*)(ws + wlb_off);
    _Float16* Wc1f = (_Float16*)(ws + wcf_off);
    _Float16* Xf   = (_Float16*)(ws + xf_off);

    phase1_kernel<<<9640, 256, 0, stream>>>(pos, W1a, b1a, W2, Wm1, Wm2, Wm3, Wl, W1b, W1c,
                                            idx, u1, v1, Wcat, Wm1T, Wm2T, Wm3T, Wlb, Wc1f);
    conv1_mfma_kernel<<<1024, 64, 0, stream>>>(idx, u1, v1, Wc1f, b1b, b1c, x1);
    sqnorm_kernel<<<64, 256, 0, stream>>>(x1, sq, Afrag, Xf);
    dist2sel_kernel<<<1024, 512, 0, stream>>>(Xf, sq, idx);
    u2v2_kernel<<<256, 256, 0, stream>>>(x1, Wcat, b2, u2, v2);
    gatherfrag_kernel<<<1024, 256, 0, stream>>>(idx, u2, v2, Afrag);
    lin1max_mfma_kernel<<<1024, 256, 0, stream>>>(Afrag, Wlb, gp);
    gmax_kernel<<<64, 256, 0, stream>>>(gp, bl, gs);
    head1_kernel<<<512, 256, 0, stream>>>(gs, Wm1T, bm1, h1);
    head2_kernel<<<256, 256, 0, stream>>>(h1, Wm2T, bm2, h2);
    head3_kernel<<<16, 256, 0, stream>>>(h2, Wm3T, bm3, out);
}

// Round 18
// 188.691 us; speedup vs baseline: 1.0422x; 1.0422x over previous
//
#include <hip/hip_runtime.h>

constexpr int NB  = 16;      // batches
constexpr int NP  = 1024;    // points per batch
constexpr int NPT = NB * NP; // 16384
constexpr int KNB = 20;

typedef unsigned short ushortT;
typedef __bf16 bf16x8 __attribute__((ext_vector_type(8)));
typedef _Float16 f16x8 __attribute__((ext_vector_type(8)));
typedef float f32x4 __attribute__((ext_vector_type(4)));

__device__ inline unsigned f2bf_pair(float f0, float f1) {
    unsigned u0 = __float_as_uint(f0); u0 = (u0 + 0x7FFFu + ((u0 >> 16) & 1u)) >> 16;
    unsigned u1 = __float_as_uint(f1); u1 = (u1 + 0x7FFFu + ((u1 >> 16) & 1u)) >> 16;
    return u0 | (u1 << 16);
}

// monotone uint32 transform: u < v  <=>  f < g
__device__ inline unsigned monokey(float f) {
    unsigned u = __float_as_uint(f);
    return u ^ ((unsigned)((int)u >> 31) | 0x80000000u);
}

// min over each 16-lane row via DPP (VALU-latency cross-lane, no DS pipe)
__device__ inline unsigned dppmin16(unsigned v) {
    unsigned t;
    t = (unsigned)__builtin_amdgcn_update_dpp((int)v, (int)v, 0xB1, 0xF, 0xF, false);  // quad [1,0,3,2]
    v = v < t ? v : t;
    t = (unsigned)__builtin_amdgcn_update_dpp((int)v, (int)v, 0x4E, 0xF, 0xF, false);  // quad [2,3,0,1]
    v = v < t ? v : t;
    t = (unsigned)__builtin_amdgcn_update_dpp((int)v, (int)v, 0x141, 0xF, 0xF, false); // row_half_mirror
    v = v < t ? v : t;
    t = (unsigned)__builtin_amdgcn_update_dpp((int)v, (int)v, 0x140, 0xF, 0xF, false); // row_mirror
    v = v < t ? v : t;
    return v;
}

// ---------------------------------------------------------------------------
// bitonic sort of 16 u64 keys, ascending (validated bit-exact in round 4)
// ---------------------------------------------------------------------------
__device__ inline void sort16_u64(unsigned long long key[16]) {
#pragma unroll
    for (int k = 2; k <= 16; k <<= 1) {
#pragma unroll
        for (int j = k >> 1; j > 0; j >>= 1) {
#pragma unroll
            for (int a = 0; a < 16; ++a) {
                int b = a ^ j;
                if (b > a) {
                    unsigned long long x = key[a], y = key[b];
                    bool lt = x < y;
                    unsigned long long mn = lt ? x : y, mx = lt ? y : x;
                    if ((a & k) == 0) { key[a] = mn; key[b] = mx; }
                    else              { key[a] = mx; key[b] = mn; }
                }
            }
        }
    }
}

// ---------------------------------------------------------------------------
// wave-wide top-20 via sorted per-lane runs + LDS-head tournament
// (knn3 variant, R12-proven: private 17-entry u64 column, sentinel at [16]).
// ---------------------------------------------------------------------------
__device__ inline void wave_top20_lds(unsigned long long key[16], int lane,
                                      unsigned long long* __restrict__ col,
                                      int* __restrict__ outp, int jadd)
{
    sort16_u64(key);
#pragma unroll
    for (int s = 0; s < 16; ++s) col[s] = key[s];
    unsigned ptr = 0;
    for (int t = 0; t < KNB; ++t) {
        unsigned long long h = col[ptr];     // ds_read_b64, per-wave in-order
        unsigned hv = (unsigned)(h >> 32);
        unsigned hj = (unsigned)h;
        unsigned r = dppmin16(hv);
        unsigned g0 = (unsigned)__builtin_amdgcn_readlane((int)r, 0);
        unsigned g1 = (unsigned)__builtin_amdgcn_readlane((int)r, 16);
        unsigned g2 = (unsigned)__builtin_amdgcn_readlane((int)r, 32);
        unsigned g3 = (unsigned)__builtin_amdgcn_readlane((int)r, 48);
        unsigned g = min(min(g0, g1), min(g2, g3));     // uniform (SGPR)
        unsigned long long ball = __ballot(hv == g);
        int wl = __ffsll(ball) - 1;                      // lowest lane = lowest j
        int wj = __builtin_amdgcn_readlane((int)hj, wl);
        if (lane == 0) outp[t] = jadd + wj;
        ptr += (lane == wl) ? 1u : 0u;                   // branchless advance
    }
}

// ---------------------------------------------------------------------------
// interleaved dual-row tournament (R16-proven): two independent selection
// chains issue in each other's stall shadows. hrow* = sorted u32 values
// slot-major (p*64+lane); perm* = original-slot nibbles.
// ---------------------------------------------------------------------------
__device__ inline void dual_tourney20(
    unsigned* __restrict__ hrow0, unsigned long long perm0,
    unsigned* __restrict__ hrow1, unsigned long long perm1,
    int lane, int* __restrict__ outA, int* __restrict__ outB, int jadd)
{
    unsigned ptrA = 0, ptrB = 0;
    unsigned curA = hrow0[lane], nxtA = hrow0[64 + lane];
    unsigned curB = hrow1[lane], nxtB = hrow1[64 + lane];
    unsigned csA = (unsigned)(perm0 & 15ull), nsA = (unsigned)((perm0 >> 4) & 15ull);
    unsigned csB = (unsigned)(perm1 & 15ull), nsB = (unsigned)((perm1 >> 4) & 15ull);
    for (int t = 0; t < KNB; ++t) {
        unsigned rmA = dppmin16(curA);
        unsigned rmB = dppmin16(curB);
        unsigned a0 = (unsigned)__builtin_amdgcn_readlane((int)rmA, 0);
        unsigned b0 = (unsigned)__builtin_amdgcn_readlane((int)rmB, 0);
        unsigned a1 = (unsigned)__builtin_amdgcn_readlane((int)rmA, 16);
        unsigned b1 = (unsigned)__builtin_amdgcn_readlane((int)rmB, 16);
        unsigned a2 = (unsigned)__builtin_amdgcn_readlane((int)rmA, 32);
        unsigned b2 = (unsigned)__builtin_amdgcn_readlane((int)rmB, 32);
        unsigned a3 = (unsigned)__builtin_amdgcn_readlane((int)rmA, 48);
        unsigned b3 = (unsigned)__builtin_amdgcn_readlane((int)rmB, 48);
        unsigned gA = min(min(a0, a1), min(a2, a3));
        unsigned gB = min(min(b0, b1), min(b2, b3));
        unsigned long long ballA = __ballot(curA == gA);
        unsigned long long ballB = __ballot(curB == gB);
        int wlA = __ffsll(ballA) - 1;
        int wlB = __ffsll(ballB) - 1;
        int jA = (lane << 4) + (int)csA;
        int jB = (lane << 4) + (int)csB;
        int wjA = __builtin_amdgcn_readlane(jA, wlA);
        int wjB = __builtin_amdgcn_readlane(jB, wlB);
        if (lane == 0) { outA[t] = jadd + wjA; outB[t] = jadd + wjB; }
        if (lane == wlA) {
            curA = nxtA; csA = nsA;
            ptrA += 1u;
            unsigned p2 = ptrA + 1u;
            unsigned p2c = p2 < 15u ? p2 : 15u;
            nsA = (unsigned)((perm0 >> (4 * (int)p2c)) & 15ull);
            nxtA = (p2 < 16u) ? hrow0[p2 * 64 + lane] : 0xFFFFFFFFu;
        }
        if (lane == wlB) {
            curB = nxtB; csB = nsB;
            ptrB += 1u;
            unsigned p2 = ptrB + 1u;
            unsigned p2c = p2 < 15u ? p2 : 15u;
            nsB = (unsigned)((perm1 >> (4 * (int)p2c)) & 15ull);
            nxtB = (p2 < 16u) ? hrow1[p2 * 64 + lane] : 0xFFFFFFFFu;
        }
    }
}

// ---------------------------------------------------------------------------
__global__ void fail_kernel(float* out, int n) {
    int i = blockIdx.x * 256 + threadIdx.x;
    if (i < n) out[i] = -777.0f;
}

// ---------------------------------------------------------------------------
// phase1 (R12-proven): fused knn3 (blocks 0..4095, 1 row/wave) +
// prep_uv1 (4096..8191) + prep_w (rest). knn3 heap = 34 KB u64 w/ sentinel.
// ---------------------------------------------------------------------------
__global__ __launch_bounds__(256) void phase1_kernel(
    const float* __restrict__ pos, const float* __restrict__ W1a, const float* __restrict__ b1a,
    const float* __restrict__ W2,
    const float* __restrict__ Wm1, const float* __restrict__ Wm2, const float* __restrict__ Wm3,
    const float* __restrict__ Wl, const float* __restrict__ W1b, const float* __restrict__ W1c,
    int* __restrict__ idx, float* __restrict__ u1, float* __restrict__ v1,
    float* __restrict__ Wcat, float* __restrict__ Wm1T, float* __restrict__ Wm2T, float* __restrict__ Wm3T,
    ushortT* __restrict__ Wlb, _Float16* __restrict__ Wc1f)
{
    __shared__ unsigned long long heap[4][64][17];
    const int bid = blockIdx.x;
    const int tid = threadIdx.x;
    if (bid < 4096) {
        const int w = tid >> 6, lane = tid & 63;
        const int b = bid >> 8;
        const int i = ((bid & 255) << 2) + w;
        const float* pb = pos + (size_t)b * NP * 3;
        float cbuf[48];
        {
            const float4* src = (const float4*)(pb + lane * 48);
#pragma unroll
            for (int q = 0; q < 12; ++q) *(float4*)&cbuf[q * 4] = src[q];
        }
        const float xi = pb[3 * i], yi = pb[3 * i + 1], zi = pb[3 * i + 2];
        const float sqi = xi * xi + yi * yi + zi * zi;
        unsigned long long key[16];
#pragma unroll
        for (int s = 0; s < 16; ++s) {
            float x = cbuf[3 * s], y = cbuf[3 * s + 1], z = cbuf[3 * s + 2];
            float d = sqi + (x * x + y * y + z * z) - 2.0f * (xi * x + yi * y + zi * z);
            int j = (lane << 4) + s;
            if (j == i) d += 1e10f;
            key[s] = ((unsigned long long)monokey(d) << 32) | (unsigned)j;
        }
        heap[w][lane][16] = ~0ULL;   // sentinel
        wave_top20_lds(key, lane, &heap[w][lane][0], idx + (size_t)(b * NP + i) * KNB, b * NP);
        return;
    }
    if (bid < 8192) {
        int id = (bid - 4096) * 256 + tid;  // 16384*64
        int i = id >> 6, c = id & 63;
        float x = pos[3 * i], y = pos[3 * i + 1], z = pos[3 * i + 2];
        float wu0 = W1a[3 * 64 + c], wu1 = W1a[4 * 64 + c], wu2 = W1a[5 * 64 + c];
        float wv0 = W1a[0 * 64 + c] - wu0, wv1 = W1a[1 * 64 + c] - wu1, wv2 = W1a[2 * 64 + c] - wu2;
        u1[id] = x * wu0 + y * wu1 + z * wu2;
        v1[id] = b1a[c] + x * wv0 + y * wv1 + z * wv2;
        return;
    }
    int id = (bid - 8192) * 256 + tid;
    if (id < 64 * 256) {
        int c = id >> 8, n = id & 255;
        float wb = W2[(64 + c) * 128 + (n & 127)];
        Wcat[id] = (n < 128) ? wb : (W2[c * 128 + (n - 128)] - wb);
        return;
    }
    id -= 64 * 256;
    if (id < 512 * 1024) { int j = id >> 10, c = id & 1023; Wm1T[id] = Wm1[c * 512 + j]; return; }
    id -= 512 * 1024;
    if (id < 256 * 512)  { int j = id >> 9,  c = id & 511;  Wm2T[id] = Wm2[c * 256 + j]; return; }
    id -= 256 * 512;
    if (id < 40 * 256)   { int j = id >> 8,  c = id & 255;  Wm3T[id] = Wm3[c * 40 + j];  return; }
    id -= 40 * 256;
    if (id < 8 * 6 * 8 * 64 * 8) {
        int j = id & 7;
        int t = id >> 3;
        int lane = t & 63; t >>= 6;
        int f = t & 7; t >>= 3;
        int s = t % 6, nt = t / 6;
        int k = s * 32 + (lane >> 4) * 8 + j;
        int n = nt * 128 + f * 16 + (lane & 15);
        unsigned u = __float_as_uint(Wl[(size_t)k * 1024 + n]);
        u = (u + 0x7FFFu + ((u >> 16) & 1u)) >> 16;
        Wlb[id] = (ushortT)u;
        return;
    }
    id -= 8 * 6 * 8 * 64 * 8;
    if (id < 16384) {
        int mat = id >> 13;
        int rem = id & 8191;
        int part = rem >> 12;
        int t = rem & 4095;
        int frag = t >> 9;
        int r = t & 511;
        int lane = r >> 3, j = r & 7;
        int kf = frag >> 2, nf = frag & 3;
        int k = kf * 32 + (lane >> 4) * 8 + j;
        int n = nf * 16 + (lane & 15);
        float w = (mat ? W1c : W1b)[k * 64 + n];
        _Float16 hi = (_Float16)w;
        Wc1f[id] = part ? (_Float16)(w - (float)hi) : hi;
        return;
    }
}

// ---------------------------------------------------------------------------
// conv1 via split-fp16 MFMA: 1 wave = 16 points, one edge per pass (20 passes).
// ---------------------------------------------------------------------------
__global__ __launch_bounds__(64, 1) void conv1_mfma_kernel(
    const int* __restrict__ idx, const float* __restrict__ u1, const float* __restrict__ v1,
    const _Float16* __restrict__ Wf, const float* __restrict__ b1b, const float* __restrict__ b1c,
    float* __restrict__ x1)
{
    __shared__ int idx_s[16 * 20];
    __shared__ __align__(16) float tr[16 * 68];    // h2 transpose buffer
    __shared__ __align__(16) float xout[16 * 68];  // final x1 staging
    const int lane = threadIdx.x;
    const int row = lane & 15, ks = lane >> 4;
    const int pbase = blockIdx.x * 16;

    for (int t = lane; t < 320; t += 64) idx_s[t] = idx[(size_t)pbase * 20 + t];

    const f16x8* Wp = (const f16x8*)Wf;
    f16x8 wbh[2][4], wbl[2][4], wch[2][4], wcl[2][4];
#pragma unroll
    for (int kf = 0; kf < 2; ++kf)
#pragma unroll
        for (int nf = 0; nf < 4; ++nf) {
            int f = kf * 4 + nf;
            wbh[kf][nf] = Wp[(0 * 8 + f) * 64 + lane];
            wbl[kf][nf] = Wp[(1 * 8 + f) * 64 + lane];
            wch[kf][nf] = Wp[(2 * 8 + f) * 64 + lane];
            wcl[kf][nf] = Wp[(3 * 8 + f) * 64 + lane];
        }
    float bb[4], bc[4];
#pragma unroll
    for (int nf = 0; nf < 4; ++nf) { bb[nf] = b1b[nf * 16 + row]; bc[nf] = b1c[nf * 16 + row]; }

    const int P = pbase + row;
    float4 v1f[4];
    {
        const float4* v4a = (const float4*)(v1 + (size_t)P * 64 + ks * 8);
        v1f[0] = v4a[0]; v1f[1] = v4a[1];
        const float4* v4b = (const float4*)(v1 + (size_t)P * 64 + 32 + ks * 8);
        v1f[2] = v4b[0]; v1f[3] = v4b[1];
    }
    f32x4 xmax[4];
#pragma unroll
    for (int nf = 0; nf < 4; ++nf) xmax[nf] = (f32x4)(-3.0e38f);

    int jn = idx_s[row * 20];
    float4 un[4];
    {
        const float4* up = (const float4*)(u1 + (size_t)jn * 64 + ks * 8);
        un[0] = up[0]; un[1] = up[1];
        const float4* up2 = (const float4*)(u1 + (size_t)jn * 64 + 32 + ks * 8);
        un[2] = up2[0]; un[3] = up2[1];
    }
    for (int e = 0; e < 20; ++e) {
        float4 uc[4] = {un[0], un[1], un[2], un[3]};
        if (e < 19) {
            jn = idx_s[row * 20 + e + 1];
            const float4* up = (const float4*)(u1 + (size_t)jn * 64 + ks * 8);
            un[0] = up[0]; un[1] = up[1];
            const float4* up2 = (const float4*)(u1 + (size_t)jn * 64 + 32 + ks * 8);
            un[2] = up2[0]; un[3] = up2[1];
        }
        f32x4 c2[4];
#pragma unroll
        for (int nf = 0; nf < 4; ++nf) c2[nf] = (f32x4)(bb[nf]);
#pragma unroll
        for (int kf = 0; kf < 2; ++kf) {
            const float* uu = (const float*)&uc[kf * 2];
            const float* vv = (const float*)&v1f[kf * 2];
            f16x8 ah, al;
#pragma unroll
            for (int q = 0; q < 8; ++q) {
                float h = fmaxf(uu[q] + vv[q], 0.f);
                _Float16 hi = (_Float16)h;
                ah[q] = hi;
                al[q] = (_Float16)(h - (float)hi);
            }
#pragma unroll
            for (int nf = 0; nf < 4; ++nf) {
                c2[nf] = __builtin_amdgcn_mfma_f32_16x16x32_f16(ah, wbh[kf][nf], c2[nf], 0, 0, 0);
                c2[nf] = __builtin_amdgcn_mfma_f32_16x16x32_f16(ah, wbl[kf][nf], c2[nf], 0, 0, 0);
                c2[nf] = __builtin_amdgcn_mfma_f32_16x16x32_f16(al, wbh[kf][nf], c2[nf], 0, 0, 0);
            }
        }
#pragma unroll
        for (int nf = 0; nf < 4; ++nf)
#pragma unroll
            for (int r = 0; r < 4; ++r)
                tr[(ks * 4 + r) * 68 + nf * 16 + row] = fmaxf(c2[nf][r], 0.f);
        __builtin_amdgcn_sched_barrier(0);
        f32x4 c3[4];
#pragma unroll
        for (int nf = 0; nf < 4; ++nf) c3[nf] = (f32x4)0.0f;
#pragma unroll
        for (int kf = 0; kf < 2; ++kf) {
            float hbuf[8];
            *(float4*)&hbuf[0] = *(const float4*)&tr[row * 68 + kf * 32 + ks * 8];
            *(float4*)&hbuf[4] = *(const float4*)&tr[row * 68 + kf * 32 + ks * 8 + 4];
            f16x8 ah, al;
#pragma unroll
            for (int q = 0; q < 8; ++q) {
                _Float16 hi = (_Float16)hbuf[q];
                ah[q] = hi;
                al[q] = (_Float16)(hbuf[q] - (float)hi);
            }
#pragma unroll
            for (int nf = 0; nf < 4; ++nf) {
                c3[nf] = __builtin_amdgcn_mfma_f32_16x16x32_f16(ah, wch[kf][nf], c3[nf], 0, 0, 0);
                c3[nf] = __builtin_amdgcn_mfma_f32_16x16x32_f16(ah, wcl[kf][nf], c3[nf], 0, 0, 0);
                c3[nf] = __builtin_amdgcn_mfma_f32_16x16x32_f16(al, wch[kf][nf], c3[nf], 0, 0, 0);
            }
        }
        __builtin_amdgcn_sched_barrier(0);
#pragma unroll
        for (int nf = 0; nf < 4; ++nf) {
            xmax[nf][0] = fmaxf(xmax[nf][0], c3[nf][0]);
            xmax[nf][1] = fmaxf(xmax[nf][1], c3[nf][1]);
            xmax[nf][2] = fmaxf(xmax[nf][2], c3[nf][2]);
            xmax[nf][3] = fmaxf(xmax[nf][3], c3[nf][3]);
        }
    }
#pragma unroll
    for (int nf = 0; nf < 4; ++nf)
#pragma unroll
        for (int r = 0; r < 4; ++r)
            xout[(ks * 4 + r) * 68 + nf * 16 + row] = xmax[nf][r] + bc[nf];
    __builtin_amdgcn_sched_barrier(0);
    {
        const int r2 = lane >> 2, c0 = (lane & 3) * 16;
#pragma unroll
        for (int q = 0; q < 4; ++q) {
            float4 v = *(const float4*)&xout[r2 * 68 + c0 + q * 4];
            *(float4*)(x1 + (size_t)(pbase + r2) * 64 + c0 + q * 4) = v;
        }
    }
}

// ---------------------------------------------------------------------------
// sq norms of x1 rows + Afrag bf16 pack (lin1max) + Xf split-fp16 frags (dist2sel)
// ---------------------------------------------------------------------------
__global__ __launch_bounds__(256) void sqnorm_kernel(
    const float* __restrict__ x1, float* __restrict__ sq,
    ushortT* __restrict__ Afrag, _Float16* __restrict__ Xf)
{
    int i = blockIdx.x * 256 + threadIdx.x;  // 16384
    const float4* r = (const float4*)(x1 + (size_t)i * 64);
    float c[64];
    float s = 0.f;
#pragma unroll
    for (int q = 0; q < 16; ++q) {
        float4 a = r[q];
        c[4 * q] = a.x; c[4 * q + 1] = a.y; c[4 * q + 2] = a.z; c[4 * q + 3] = a.w;
        s += a.x * a.x + a.y * a.y + a.z * a.z + a.w * a.w;
    }
    sq[i] = s;
    const size_t t = i >> 4;
#pragma unroll
    for (int cb = 0; cb < 8; ++cb) {
        uint4 pk;
        pk.x = f2bf_pair(c[8 * cb + 0], c[8 * cb + 1]);
        pk.y = f2bf_pair(c[8 * cb + 2], c[8 * cb + 3]);
        pk.z = f2bf_pair(c[8 * cb + 4], c[8 * cb + 5]);
        pk.w = f2bf_pair(c[8 * cb + 6], c[8 * cb + 7]);
        size_t af = (t * 6 + (cb >> 2)) * 512 + (size_t)((cb & 3) * 16 + (i & 15)) * 8;
        *(uint4*)(Afrag + af) = pk;
        int kf = cb >> 2;
        int lanef = ((cb & 3) << 4) + (i & 15);
        __align__(16) _Float16 hbuf[8];
        __align__(16) _Float16 lbuf[8];
#pragma unroll
        for (int q2 = 0; q2 < 8; ++q2) {
            float v = c[cb * 8 + q2];
            _Float16 hi = (_Float16)v;
            hbuf[q2] = hi;
            lbuf[q2] = (_Float16)(v - (float)hi);
        }
        *(uint4*)(Xf + ((t * 2 + kf) * 2 + 0) * 512 + (size_t)lanef * 8) = *(uint4*)hbuf;
        *(uint4*)(Xf + ((t * 2 + kf) * 2 + 1) * 512 + (size_t)lanef * 8) = *(uint4*)lbuf;
    }
}

// ---------------------------------------------------------------------------
// dist2sel v6 (R16-proven): 8 waves/block (512 thr); wave owns 2 rows; sorts
// sequential, tournaments INTERLEAVED. LDS 64 KB stride 1024.
// ---------------------------------------------------------------------------
__global__ __launch_bounds__(512, 2) void dist2sel_kernel(
    const _Float16* __restrict__ Xf, const float* __restrict__ sq, int* __restrict__ idx)
{
    __shared__ unsigned kls[16 * 1024];   // 64 KB
    const int tid = threadIdx.x;
    const int w = tid >> 6, lane = tid & 63;   // w in 0..7
    const int b = blockIdx.x >> 6;
    const int rowtile = blockIdx.x & 63;
    const int c15 = lane & 15;
    const int rbase = (lane >> 4) * 4;

    const f16x8* Xv = (const f16x8*)Xf;
    const int tA = b * 64 + rowtile;
    f16x8 ah[2], al[2];
#pragma unroll
    for (int kf = 0; kf < 2; ++kf) {
        ah[kf] = Xv[((size_t)(tA * 2 + kf) * 2 + 0) * 64 + lane];
        al[kf] = Xv[((size_t)(tA * 2 + kf) * 2 + 1) * 64 + lane];
    }
    const float* sqb = sq + (size_t)b * NP;
    float sqi[4];
#pragma unroll
    for (int rr = 0; rr < 4; ++rr)
        sqi[rr] = sqb[rowtile * 16 + rbase + rr];

    for (int q = 0; q < 8; ++q) {
        const int ct = w * 8 + q;
        const int tB = b * 64 + ct;
        f16x8 bh0 = Xv[((size_t)(tB * 2 + 0) * 2 + 0) * 64 + lane];
        f16x8 bl0 = Xv[((size_t)(tB * 2 + 0) * 2 + 1) * 64 + lane];
        f16x8 bh1 = Xv[((size_t)(tB * 2 + 1) * 2 + 0) * 64 + lane];
        f16x8 bl1 = Xv[((size_t)(tB * 2 + 1) * 2 + 1) * 64 + lane];
        const int col = ct * 16 + c15;
        const float sqj = sqb[col];
        f32x4 acc = (f32x4)0.0f;
        acc = __builtin_amdgcn_mfma_f32_16x16x32_f16(ah[0], bh0, acc, 0, 0, 0);
        acc = __builtin_amdgcn_mfma_f32_16x16x32_f16(ah[0], bl0, acc, 0, 0, 0);
        acc = __builtin_amdgcn_mfma_f32_16x16x32_f16(al[0], bh0, acc, 0, 0, 0);
        acc = __builtin_amdgcn_mfma_f32_16x16x32_f16(ah[1], bh1, acc, 0, 0, 0);
        acc = __builtin_amdgcn_mfma_f32_16x16x32_f16(ah[1], bl1, acc, 0, 0, 0);
        acc = __builtin_amdgcn_mfma_f32_16x16x32_f16(al[1], bh1, acc, 0, 0, 0);
        const int pc = col ^ ((col >> 6) & 15);   // bank swizzle (bijective per 64-col block)
#pragma unroll
        for (int rr = 0; rr < 4; ++rr) {
            float d = sqi[rr] + sqj - 2.0f * acc[rr];
            if (rowtile * 16 + rbase + rr == col) d += 1e10f;
            kls[(rbase + rr) * 1024 + pc] = monokey(d);
        }
    }
    __syncthreads();

    const int gb = b * NP;
    const int r0 = 2 * w, r1 = 2 * w + 1;
    unsigned* hrow0 = &kls[r0 * 1024];
    unsigned* hrow1 = &kls[r1 * 1024];
    unsigned long long perm0 = 0, perm1 = 0;
    {
        unsigned long long key[16];
#pragma unroll
        for (int s = 0; s < 16; ++s) {
            int col = (lane << 4) + s;
            int pc = col ^ ((col >> 6) & 15);
            key[s] = ((unsigned long long)kls[r0 * 1024 + pc] << 32) | (unsigned)col;
        }
        sort16_u64(key);
#pragma unroll
        for (int p = 0; p < 16; ++p) {
            hrow0[p * 64 + lane] = (unsigned)(key[p] >> 32);
            perm0 |= (unsigned long long)((unsigned)key[p] & 15u) << (4 * p);
        }
    }
    {
        unsigned long long key[16];
#pragma unroll
        for (int s = 0; s < 16; ++s) {
            int col = (lane << 4) + s;
            int pc = col ^ ((col >> 6) & 15);
            key[s] = ((unsigned long long)kls[r1 * 1024 + pc] << 32) | (unsigned)col;
        }
        sort16_u64(key);
#pragma unroll
        for (int p = 0; p < 16; ++p) {
            hrow1[p * 64 + lane] = (unsigned)(key[p] >> 32);
            perm1 |= (unsigned long long)((unsigned)key[p] & 15u) << (4 * p);
        }
    }
    dual_tourney20(hrow0, perm0, hrow1, perm1, lane,
                   idx + (size_t)(gb + rowtile * 16 + r0) * KNB,
                   idx + (size_t)(gb + rowtile * 16 + r1) * KNB, gb);
}

// ---------------------------------------------------------------------------
// u2/v2 GEMM: [16384 x 64] @ Wcat[64 x 256] -> u2 (n<128), v2 (+b2, n>=128)
// ---------------------------------------------------------------------------
__global__ __launch_bounds__(256) void u2v2_kernel(
    const float* __restrict__ x1, const float* __restrict__ Wcat, const float* __restrict__ b2,
    float* __restrict__ u2, float* __restrict__ v2)
{
    __shared__ float aT[32][132];
    __shared__ float bW[32][132];
    const int tid = threadIdx.x;
    const int mt = blockIdx.x >> 1, nt = blockIdx.x & 1;
    const int m0 = mt << 7, n0 = nt << 7;
    const int ti = tid >> 4, tj = tid & 15;
    float acc[8][8];
#pragma unroll
    for (int a = 0; a < 8; ++a)
#pragma unroll
        for (int q = 0; q < 8; ++q) acc[a][q] = 0.f;
    for (int ct = 0; ct < 2; ++ct) {
        __syncthreads();
#pragma unroll
        for (int rep = 0; rep < 4; ++rep) {
            int f = tid + (rep << 8);
            { int r = f >> 3, q = f & 7;
              float4 v = *(const float4*)(x1 + (size_t)(m0 + r) * 64 + ct * 32 + q * 4);
              aT[4 * q + 0][r] = v.x; aT[4 * q + 1][r] = v.y; aT[4 * q + 2][r] = v.z; aT[4 * q + 3][r] = v.w; }
            { int cc = f >> 5, q = f & 31;
              *(float4*)&bW[cc][4 * q] = *(const float4*)(Wcat + (size_t)(ct * 32 + cc) * 256 + n0 + q * 4); }
        }
        __syncthreads();
#pragma unroll 4
        for (int c = 0; c < 32; ++c) {
            float af[8], bf[8];
            *(float4*)&af[0] = *(const float4*)&aT[c][ti * 8];
            *(float4*)&af[4] = *(const float4*)&aT[c][ti * 8 + 4];
            *(float4*)&bf[0] = *(const float4*)&bW[c][tj * 8];
            *(float4*)&bf[4] = *(const float4*)&bW[c][tj * 8 + 4];
#pragma unroll
            for (int a = 0; a < 8; ++a)
#pragma unroll
                for (int q = 0; q < 8; ++q) acc[a][q] = fmaf(af[a], bf[q], acc[a][q]);
        }
    }
#pragma unroll
    for (int a = 0; a < 8; ++a) {
        int m = m0 + ti * 8 + a;
        if (n0 < 128) {
            float outv[8];
#pragma unroll
            for (int q = 0; q < 8; ++q) outv[q] = acc[a][q];
            *(float4*)(u2 + (size_t)m * 128 + n0 + tj * 8)     = *(float4*)&outv[0];
            *(float4*)(u2 + (size_t)m * 128 + n0 + tj * 8 + 4) = *(float4*)&outv[4];
        } else {
            float outv[8];
#pragma unroll
            for (int q = 0; q < 8; ++q) outv[q] = acc[a][q] + b2[n0 - 128 + tj * 8 + q];
            *(float4*)(v2 + (size_t)m * 128 + (n0 - 128) + tj * 8)     = *(float4*)&outv[0];
            *(float4*)(v2 + (size_t)m * 128 + (n0 - 128) + tj * 8 + 4) = *(float4*)&outv[4];
        }
    }
}

// ---------------------------------------------------------------------------
// conv2 gather-max -> Afrag k=64..191 (bf16 fragment layout), x2 never stored
// ---------------------------------------------------------------------------
__global__ __launch_bounds__(256) void gatherfrag_kernel(
    const int* __restrict__ idx, const float* __restrict__ u2,
    const float* __restrict__ v2, ushortT* __restrict__ Afrag)
{
    const int tid = threadIdx.x;
    const int i = blockIdx.x * 16 + (tid >> 4);
    const int cb = tid & 15;
    const int* ib = idx + (size_t)i * KNB;
    float m[8];
#pragma unroll
    for (int d = 0; d < 8; ++d) m[d] = -3e38f;
    for (int e = 0; e < KNB; ++e) {
        int j = ib[e];
        const float4* p = (const float4*)(u2 + (size_t)j * 128 + cb * 8);
        float4 a = p[0], b = p[1];
        m[0] = fmaxf(m[0], a.x); m[1] = fmaxf(m[1], a.y); m[2] = fmaxf(m[2], a.z); m[3] = fmaxf(m[3], a.w);
        m[4] = fmaxf(m[4], b.x); m[5] = fmaxf(m[5], b.y); m[6] = fmaxf(m[6], b.z); m[7] = fmaxf(m[7], b.w);
    }
    const float4* vp = (const float4*)(v2 + (size_t)i * 128 + cb * 8);
    float4 va = vp[0], vb = vp[1];
    m[0] += va.x; m[1] += va.y; m[2] += va.z; m[3] += va.w;
    m[4] += vb.x; m[5] += vb.y; m[6] += vb.z; m[7] += vb.w;
    uint4 pk;
    pk.x = f2bf_pair(m[0], m[1]);
    pk.y = f2bf_pair(m[2], m[3]);
    pk.z = f2bf_pair(m[4], m[5]);
    pk.w = f2bf_pair(m[6], m[7]);
    size_t af = ((size_t)(i >> 4) * 6 + 2 + (cb >> 2)) * 512 + (size_t)((cb & 3) * 16 + (i & 15)) * 8;
    *(uint4*)(Afrag + af) = pk;
}

// ---------------------------------------------------------------------------
// lin1 + global max pool via bf16 MFMA.
// ---------------------------------------------------------------------------
__global__ __launch_bounds__(256) void lin1max_mfma_kernel(
    const ushortT* __restrict__ Afrag, const ushortT* __restrict__ Wlb, float* __restrict__ gp)
{
    __shared__ float red[4][128];
    const int tid = threadIdx.x;
    const int w = tid >> 6, lane = tid & 63;
    const int nt = blockIdx.x & 7;
    const int rt = (blockIdx.x >> 3) & 7;
    const int b  = blockIdx.x >> 6;
    const int rt16 = ((b << 3) + rt) * 8 + (w << 1);
    const bf16x8* Ap = (const bf16x8*)Afrag;
    const bf16x8* Bp = (const bf16x8*)Wlb;
    f32x4 acc[2][8];
#pragma unroll
    for (int mm = 0; mm < 2; ++mm)
#pragma unroll
        for (int f = 0; f < 8; ++f) acc[mm][f] = (f32x4)0.0f;
#pragma unroll
    for (int s = 0; s < 6; ++s) {
        bf16x8 a0 = Ap[((rt16    ) * 6 + s) * 64 + lane];
        bf16x8 a1 = Ap[((rt16 + 1) * 6 + s) * 64 + lane];
#pragma unroll
        for (int f = 0; f < 8; ++f) {
            bf16x8 bb = Bp[(((nt * 6 + s) << 3) + f) * 64 + lane];
            acc[0][f] = __builtin_amdgcn_mfma_f32_16x16x32_bf16(a0, bb, acc[0][f], 0, 0, 0);
            acc[1][f] = __builtin_amdgcn_mfma_f32_16x16x32_bf16(a1, bb, acc[1][f], 0, 0, 0);
        }
    }
#pragma unroll
    for (int f = 0; f < 8; ++f) {
        float m = acc[0][f][0];
        m = fmaxf(m, acc[0][f][1]); m = fmaxf(m, acc[0][f][2]); m = fmaxf(m, acc[0][f][3]);
        m = fmaxf(m, acc[1][f][0]); m = fmaxf(m, acc[1][f][1]);
        m = fmaxf(m, acc[1][f][2]); m = fmaxf(m, acc[1][f][3]);
        m = fmaxf(m, __shfl_xor(m, 16, 64));
        m = fmaxf(m, __shfl_xor(m, 32, 64));
        if (lane < 16) red[w][f * 16 + lane] = m;
    }
    __syncthreads();
    if (tid < 128) {
        float m = fmaxf(fmaxf(red[0][tid], red[1][tid]), fmaxf(red[2][tid], red[3][tid]));
        gp[((size_t)rt * NB + b) * 1024 + nt * 128 + tid] = m;
    }
}

// ---------------------------------------------------------------------------
// head stage 0: gs[b][c] = max over 8 gp parts + bl[c]   (16x1024)
// ---------------------------------------------------------------------------
__global__ __launch_bounds__(256) void gmax_kernel(
    const float* __restrict__ gp, const float* __restrict__ bl, float* __restrict__ gs)
{
    int id = blockIdx.x * 256 + threadIdx.x;   // 16384
    int b = id >> 10, c = id & 1023;
    float m = gp[(size_t)b * 1024 + c];
#pragma unroll
    for (int part = 1; part < 8; ++part)
        m = fmaxf(m, gp[((size_t)part * NB + b) * 1024 + c]);
    gs[(size_t)b * 1024 + c] = m + bl[c];
}

// ---------------------------------------------------------------------------
// head stage 1: h1[b][j] = relu(gs[b] . Wm1T[j] + bm1[j]); one block per j.
// ---------------------------------------------------------------------------
__global__ __launch_bounds__(256) void head1_kernel(
    const float* __restrict__ gs, const float* __restrict__ Wm1T, const float* __restrict__ bm1,
    float* __restrict__ h1)
{
    __shared__ float red[16][17];
    const int j = blockIdx.x;                  // 0..511
    const int t = threadIdx.x;
    const int b = t >> 4, seg = t & 15;
    const float4* wr = (const float4*)(Wm1T + (size_t)j * 1024 + seg * 64);
    const float4* gr = (const float4*)(gs + (size_t)b * 1024 + seg * 64);
    float acc = 0.f;
#pragma unroll
    for (int q = 0; q < 16; ++q) {
        float4 w = wr[q], g = gr[q];
        acc = fmaf(w.x, g.x, acc); acc = fmaf(w.y, g.y, acc);
        acc = fmaf(w.z, g.z, acc); acc = fmaf(w.w, g.w, acc);
    }
    red[b][seg] = acc;
    __syncthreads();
    if (t < 16) {
        float s = 0.f;
#pragma unroll
        for (int k = 0; k < 16; ++k) s += red[t][k];
        h1[(size_t)t * 512 + j] = fmaxf(s + bm1[j], 0.f);
    }
}

// ---------------------------------------------------------------------------
// head stage 2: h2[b][j] = relu(h1[b] . Wm2T[j] + bm2[j]); one block per j.
// ---------------------------------------------------------------------------
__global__ __launch_bounds__(256) void head2_kernel(
    const float* __restrict__ h1, const float* __restrict__ Wm2T, const float* __restrict__ bm2,
    float* __restrict__ h2)
{
    __shared__ float red[16][17];
    const int j = blockIdx.x;                  // 0..255
    const int t = threadIdx.x;
    const int b = t >> 4, seg = t & 15;
    const float4* wr = (const float4*)(Wm2T + (size_t)j * 512 + seg * 32);
    const float4* hr = (const float4*)(h1 + (size_t)b * 512 + seg * 32);
    float acc = 0.f;
#pragma unroll
    for (int q = 0; q < 8; ++q) {
        float4 w = wr[q], g = hr[q];
        acc = fmaf(w.x, g.x, acc); acc = fmaf(w.y, g.y, acc);
        acc = fmaf(w.z, g.z, acc); acc = fmaf(w.w, g.w, acc);
    }
    red[b][seg] = acc;
    __syncthreads();
    if (t < 16) {
        float s = 0.f;
#pragma unroll
        for (int k = 0; k < 16; ++k) s += red[t][k];
        h2[(size_t)t * 256 + j] = fmaxf(s + bm2[j], 0.f);
    }
}

// ---------------------------------------------------------------------------
// head stage 3: logits + log_softmax; one block per batch.
// ---------------------------------------------------------------------------
__global__ __launch_bounds__(256) void head3_kernel(
    const float* __restrict__ h2, const float* __restrict__ Wm3T, const float* __restrict__ bm3,
    float* __restrict__ out)
{
    __shared__ float lg[64];
    const int tid = threadIdx.x;
    const int b = blockIdx.x;
    if (tid < 40) {
        float acc = bm3[tid];
        const float4* wr = (const float4*)(Wm3T + (size_t)tid * 256);
        const float4* hr = (const float4*)(h2 + (size_t)b * 256);
#pragma unroll
        for (int c4 = 0; c4 < 64; ++c4) {
            float4 w = wr[c4];
            float4 g4 = hr[c4];
            acc = fmaf(w.x, g4.x, acc); acc = fmaf(w.y, g4.y, acc);
            acc = fmaf(w.z, g4.z, acc); acc = fmaf(w.w, g4.w, acc);
        }
        lg[tid] = acc;
    }
    __syncthreads();
    if (tid < 64) {
        float v = (tid < 40) ? lg[tid] : -3e38f;
        float m = v;
        for (int off = 32; off; off >>= 1) m = fmaxf(m, __shfl_xor(m, off, 64));
        float ex = (tid < 40) ? expf(v - m) : 0.f;
        float s = ex;
        for (int off = 32; off; off >>= 1) s += __shfl_xor(s, off, 64);
        if (tid < 40) out[b * 40 + tid] = v - m - logf(s);
    }
}

// ---------------------------------------------------------------------------
extern "C" void kernel_launch(void* const* d_in, const int* in_sizes, int n_in,
                              void* d_out, int out_size, void* d_ws, size_t ws_size,
                              hipStream_t stream)
{
    const float* pos = (const float*)d_in[0];
    const float* W1a = (const float*)d_in[1];
    const float* b1a = (const float*)d_in[2];
    const float* W1b = (const float*)d_in[3];
    const float* b1b = (const float*)d_in[4];
    const float* W1c = (const float*)d_in[5];
    const float* b1c = (const float*)d_in[6];
    const float* W2  = (const float*)d_in[7];
    const float* b2  = (const float*)d_in[8];
    const float* Wl  = (const float*)d_in[9];
    const float* bl  = (const float*)d_in[10];
    const float* Wm1 = (const float*)d_in[11];
    const float* bm1 = (const float*)d_in[12];
    const float* Wm2 = (const float*)d_in[13];
    const float* bm2 = (const float*)d_in[14];
    const float* Wm3 = (const float*)d_in[15];
    const float* bm3 = (const float*)d_in[16];
    float* out = (float*)d_out;

    char* ws = (char*)d_ws;
    const size_t MB = 1024 * 1024;
    size_t off = 0;
    auto alloc = [&](size_t bytes) { size_t o = off; off += (bytes + 255) & ~(size_t)255; return o; };
    size_t u2_off  = alloc(8 * MB);          // u1 (4MB) then u2 (8MB)
    size_t v2_off  = alloc(8 * MB);          // v1 (4MB) then v2 (8MB)
    size_t x1_off  = alloc(4 * MB);
    size_t idx_off = alloc((size_t)NPT * KNB * 4);
    size_t sq_off  = alloc((size_t)NPT * 4);
    size_t gp_off  = alloc((size_t)8 * NB * 1024 * 4);
    size_t gs_off  = alloc((size_t)NB * 1024 * 4);
    size_t h1_off  = alloc((size_t)NB * 512 * 4);
    size_t h2_off  = alloc((size_t)NB * 256 * 4);
    size_t wc_off  = alloc(64 * 256 * 4);
    size_t w1t_off = alloc(512 * 1024 * 4);
    size_t w2t_off = alloc(256 * 512 * 4);
    size_t w3t_off = alloc(40 * 256 * 4);
    size_t af_off  = alloc((size_t)(NPT / 16) * 6 * 512 * 2);  // 6 MB bf16 A-fragments
    size_t wlb_off = alloc((size_t)8 * 6 * 8 * 512 * 2);       // 384 KB bf16 Wl fragments
    size_t wcf_off = alloc((size_t)16384 * 2);                 // 32 KB split-fp16 conv1 W frags
    size_t xf_off  = alloc((size_t)(NPT / 16) * 2 * 2 * 512 * 2); // 4 MB split-fp16 x1 frags
    if (ws_size < off) { fail_kernel<<<3, 256, 0, stream>>>(out, out_size); return; }

    float* u1    = (float*)(ws + u2_off);
    float* v1    = (float*)(ws + v2_off);
    float* u2    = (float*)(ws + u2_off);
    float* v2    = (float*)(ws + v2_off);
    float* x1    = (float*)(ws + x1_off);
    int*   idx   = (int*)(ws + idx_off);
    float* sq    = (float*)(ws + sq_off);
    float* gp    = (float*)(ws + gp_off);
    float* gs    = (float*)(ws + gs_off);
    float* h1    = (float*)(ws + h1_off);
    float* h2    = (float*)(ws + h2_off);
    float* Wcat  = (float*)(ws + wc_off);
    float* Wm1T  = (float*)(ws + w1t_off);
    float* Wm2T  = (float*)(ws + w2t_off);
    float* Wm3T  = (float*)(ws + w3t_off);
    ushortT* Afrag = (ushortT*)(ws + af_off);
    ushortT* Wlb   = (ushortT*)(ws + wlb_off);
    _Float16* Wc1f = (_Float16*)(ws + wcf_off);
    _Float16* Xf   = (_Float16*)(ws + xf_off);

    phase1_kernel<<<11688, 256, 0, stream>>>(pos, W1a, b1a, W2, Wm1, Wm2, Wm3, Wl, W1b, W1c,
                                             idx, u1, v1, Wcat, Wm1T, Wm2T, Wm3T, Wlb, Wc1f);
    conv1_mfma_kernel<<<1024, 64, 0, stream>>>(idx, u1, v1, Wc1f, b1b, b1c, x1);
    sqnorm_kernel<<<64, 256, 0, stream>>>(x1, sq, Afrag, Xf);
    dist2sel_kernel<<<1024, 512, 0, stream>>>(Xf, sq, idx);
    u2v2_kernel<<<256, 256, 0, stream>>>(x1, Wcat, b2, u2, v2);
    gatherfrag_kernel<<<1024, 256, 0, stream>>>(idx, u2, v2, Afrag);
    lin1max_mfma_kernel<<<1024, 256, 0, stream>>>(Afrag, Wlb, gp);
    gmax_kernel<<<64, 256, 0, stream>>>(gp, bl, gs);
    head1_kernel<<<512, 256, 0, stream>>>(gs, Wm1T, bm1, h1);
    head2_kernel<<<256, 256, 0, stream>>>(h1, Wm2T, bm2, h2);
    head3_kernel<<<16, 256, 0, stream>>>(h2, Wm3T, bm3, out);
}

// Round 19
// 185.898 us; speedup vs baseline: 1.0579x; 1.0150x over previous
//
#include <hip/hip_runtime.h>

constexpr int NB  = 16;      // batches
constexpr int NP  = 1024;    // points per batch
constexpr int NPT = NB * NP; // 16384
constexpr int KNB = 20;

typedef unsigned short ushortT;
typedef __bf16 bf16x8 __attribute__((ext_vector_type(8)));
typedef _Float16 f16x8 __attribute__((ext_vector_type(8)));
typedef float f32x4 __attribute__((ext_vector_type(4)));

__device__ inline unsigned f2bf_pair(float f0, float f1) {
    unsigned u0 = __float_as_uint(f0); u0 = (u0 + 0x7FFFu + ((u0 >> 16) & 1u)) >> 16;
    unsigned u1 = __float_as_uint(f1); u1 = (u1 + 0x7FFFu + ((u1 >> 16) & 1u)) >> 16;
    return u0 | (u1 << 16);
}

// monotone uint32 transform: u < v  <=>  f < g
__device__ inline unsigned monokey(float f) {
    unsigned u = __float_as_uint(f);
    return u ^ ((unsigned)((int)u >> 31) | 0x80000000u);
}

// min over each 16-lane row via DPP (VALU-latency cross-lane, no DS pipe)
__device__ inline unsigned dppmin16(unsigned v) {
    unsigned t;
    t = (unsigned)__builtin_amdgcn_update_dpp((int)v, (int)v, 0xB1, 0xF, 0xF, false);  // quad [1,0,3,2]
    v = v < t ? v : t;
    t = (unsigned)__builtin_amdgcn_update_dpp((int)v, (int)v, 0x4E, 0xF, 0xF, false);  // quad [2,3,0,1]
    v = v < t ? v : t;
    t = (unsigned)__builtin_amdgcn_update_dpp((int)v, (int)v, 0x141, 0xF, 0xF, false); // row_half_mirror
    v = v < t ? v : t;
    t = (unsigned)__builtin_amdgcn_update_dpp((int)v, (int)v, 0x140, 0xF, 0xF, false); // row_mirror
    v = v < t ? v : t;
    return v;
}

// ---------------------------------------------------------------------------
// bitonic sort of 16 u64 keys, ascending (validated bit-exact in round 4)
// ---------------------------------------------------------------------------
__device__ inline void sort16_u64(unsigned long long key[16]) {
#pragma unroll
    for (int k = 2; k <= 16; k <<= 1) {
#pragma unroll
        for (int j = k >> 1; j > 0; j >>= 1) {
#pragma unroll
            for (int a = 0; a < 16; ++a) {
                int b = a ^ j;
                if (b > a) {
                    unsigned long long x = key[a], y = key[b];
                    bool lt = x < y;
                    unsigned long long mn = lt ? x : y, mx = lt ? y : x;
                    if ((a & k) == 0) { key[a] = mn; key[b] = mx; }
                    else              { key[a] = mx; key[b] = mn; }
                }
            }
        }
    }
}

// ---------------------------------------------------------------------------
// wave-wide top-20 via sorted per-lane runs + LDS-head tournament
// (knn3 variant, R12-proven: private 17-entry u64 column, sentinel at [16]).
// ---------------------------------------------------------------------------
__device__ inline void wave_top20_lds(unsigned long long key[16], int lane,
                                      unsigned long long* __restrict__ col,
                                      int* __restrict__ outp, int jadd)
{
    sort16_u64(key);
#pragma unroll
    for (int s = 0; s < 16; ++s) col[s] = key[s];
    unsigned ptr = 0;
    for (int t = 0; t < KNB; ++t) {
        unsigned long long h = col[ptr];     // ds_read_b64, per-wave in-order
        unsigned hv = (unsigned)(h >> 32);
        unsigned hj = (unsigned)h;
        unsigned r = dppmin16(hv);
        unsigned g0 = (unsigned)__builtin_amdgcn_readlane((int)r, 0);
        unsigned g1 = (unsigned)__builtin_amdgcn_readlane((int)r, 16);
        unsigned g2 = (unsigned)__builtin_amdgcn_readlane((int)r, 32);
        unsigned g3 = (unsigned)__builtin_amdgcn_readlane((int)r, 48);
        unsigned g = min(min(g0, g1), min(g2, g3));     // uniform (SGPR)
        unsigned long long ball = __ballot(hv == g);
        int wl = __ffsll(ball) - 1;                      // lowest lane = lowest j
        int wj = __builtin_amdgcn_readlane((int)hj, wl);
        if (lane == 0) outp[t] = jadd + wj;
        ptr += (lane == wl) ? 1u : 0u;                   // branchless advance
    }
}

// ---------------------------------------------------------------------------
// interleaved dual-row tournament (R16-proven)
// ---------------------------------------------------------------------------
__device__ inline void dual_tourney20(
    unsigned* __restrict__ hrow0, unsigned long long perm0,
    unsigned* __restrict__ hrow1, unsigned long long perm1,
    int lane, int* __restrict__ outA, int* __restrict__ outB, int jadd)
{
    unsigned ptrA = 0, ptrB = 0;
    unsigned curA = hrow0[lane], nxtA = hrow0[64 + lane];
    unsigned curB = hrow1[lane], nxtB = hrow1[64 + lane];
    unsigned csA = (unsigned)(perm0 & 15ull), nsA = (unsigned)((perm0 >> 4) & 15ull);
    unsigned csB = (unsigned)(perm1 & 15ull), nsB = (unsigned)((perm1 >> 4) & 15ull);
    for (int t = 0; t < KNB; ++t) {
        unsigned rmA = dppmin16(curA);
        unsigned rmB = dppmin16(curB);
        unsigned a0 = (unsigned)__builtin_amdgcn_readlane((int)rmA, 0);
        unsigned b0 = (unsigned)__builtin_amdgcn_readlane((int)rmB, 0);
        unsigned a1 = (unsigned)__builtin_amdgcn_readlane((int)rmA, 16);
        unsigned b1 = (unsigned)__builtin_amdgcn_readlane((int)rmB, 16);
        unsigned a2 = (unsigned)__builtin_amdgcn_readlane((int)rmA, 32);
        unsigned b2 = (unsigned)__builtin_amdgcn_readlane((int)rmB, 32);
        unsigned a3 = (unsigned)__builtin_amdgcn_readlane((int)rmA, 48);
        unsigned b3 = (unsigned)__builtin_amdgcn_readlane((int)rmB, 48);
        unsigned gA = min(min(a0, a1), min(a2, a3));
        unsigned gB = min(min(b0, b1), min(b2, b3));
        unsigned long long ballA = __ballot(curA == gA);
        unsigned long long ballB = __ballot(curB == gB);
        int wlA = __ffsll(ballA) - 1;
        int wlB = __ffsll(ballB) - 1;
        int jA = (lane << 4) + (int)csA;
        int jB = (lane << 4) + (int)csB;
        int wjA = __builtin_amdgcn_readlane(jA, wlA);
        int wjB = __builtin_amdgcn_readlane(jB, wlB);
        if (lane == 0) { outA[t] = jadd + wjA; outB[t] = jadd + wjB; }
        if (lane == wlA) {
            curA = nxtA; csA = nsA;
            ptrA += 1u;
            unsigned p2 = ptrA + 1u;
            unsigned p2c = p2 < 15u ? p2 : 15u;
            nsA = (unsigned)((perm0 >> (4 * (int)p2c)) & 15ull);
            nxtA = (p2 < 16u) ? hrow0[p2 * 64 + lane] : 0xFFFFFFFFu;
        }
        if (lane == wlB) {
            curB = nxtB; csB = nsB;
            ptrB += 1u;
            unsigned p2 = ptrB + 1u;
            unsigned p2c = p2 < 15u ? p2 : 15u;
            nsB = (unsigned)((perm1 >> (4 * (int)p2c)) & 15ull);
            nxtB = (p2 < 16u) ? hrow1[p2 * 64 + lane] : 0xFFFFFFFFu;
        }
    }
}

// ---------------------------------------------------------------------------
__global__ void fail_kernel(float* out, int n) {
    int i = blockIdx.x * 256 + threadIdx.x;
    if (i < n) out[i] = -777.0f;
}

// ---------------------------------------------------------------------------
// phase1 (R12-proven): fused knn3 (blocks 0..4095, 1 row/wave) +
// prep_uv1 (4096..8191) + prep_w (rest). knn3 heap = 34 KB u64 w/ sentinel.
// ---------------------------------------------------------------------------
__global__ __launch_bounds__(256) void phase1_kernel(
    const float* __restrict__ pos, const float* __restrict__ W1a, const float* __restrict__ b1a,
    const float* __restrict__ W2,
    const float* __restrict__ Wm1, const float* __restrict__ Wm2, const float* __restrict__ Wm3,
    const float* __restrict__ Wl, const float* __restrict__ W1b, const float* __restrict__ W1c,
    int* __restrict__ idx, float* __restrict__ u1, float* __restrict__ v1,
    float* __restrict__ Wcat, float* __restrict__ Wm1T, float* __restrict__ Wm2T, float* __restrict__ Wm3T,
    ushortT* __restrict__ Wlb, _Float16* __restrict__ Wc1f)
{
    __shared__ unsigned long long heap[4][64][17];
    const int bid = blockIdx.x;
    const int tid = threadIdx.x;
    if (bid < 4096) {
        const int w = tid >> 6, lane = tid & 63;
        const int b = bid >> 8;
        const int i = ((bid & 255) << 2) + w;
        const float* pb = pos + (size_t)b * NP * 3;
        float cbuf[48];
        {
            const float4* src = (const float4*)(pb + lane * 48);
#pragma unroll
            for (int q = 0; q < 12; ++q) *(float4*)&cbuf[q * 4] = src[q];
        }
        const float xi = pb[3 * i], yi = pb[3 * i + 1], zi = pb[3 * i + 2];
        const float sqi = xi * xi + yi * yi + zi * zi;
        unsigned long long key[16];
#pragma unroll
        for (int s = 0; s < 16; ++s) {
            float x = cbuf[3 * s], y = cbuf[3 * s + 1], z = cbuf[3 * s + 2];
            float d = sqi + (x * x + y * y + z * z) - 2.0f * (xi * x + yi * y + zi * z);
            int j = (lane << 4) + s;
            if (j == i) d += 1e10f;
            key[s] = ((unsigned long long)monokey(d) << 32) | (unsigned)j;
        }
        heap[w][lane][16] = ~0ULL;   // sentinel
        wave_top20_lds(key, lane, &heap[w][lane][0], idx + (size_t)(b * NP + i) * KNB, b * NP);
        return;
    }
    if (bid < 8192) {
        int id = (bid - 4096) * 256 + tid;  // 16384*64
        int i = id >> 6, c = id & 63;
        float x = pos[3 * i], y = pos[3 * i + 1], z = pos[3 * i + 2];
        float wu0 = W1a[3 * 64 + c], wu1 = W1a[4 * 64 + c], wu2 = W1a[5 * 64 + c];
        float wv0 = W1a[0 * 64 + c] - wu0, wv1 = W1a[1 * 64 + c] - wu1, wv2 = W1a[2 * 64 + c] - wu2;
        u1[id] = x * wu0 + y * wu1 + z * wu2;
        v1[id] = b1a[c] + x * wv0 + y * wv1 + z * wv2;
        return;
    }
    int id = (bid - 8192) * 256 + tid;
    if (id < 64 * 256) {
        int c = id >> 8, n = id & 255;
        float wb = W2[(64 + c) * 128 + (n & 127)];
        Wcat[id] = (n < 128) ? wb : (W2[c * 128 + (n - 128)] - wb);
        return;
    }
    id -= 64 * 256;
    if (id < 512 * 1024) { int j = id >> 10, c = id & 1023; Wm1T[id] = Wm1[c * 512 + j]; return; }
    id -= 512 * 1024;
    if (id < 256 * 512)  { int j = id >> 9,  c = id & 511;  Wm2T[id] = Wm2[c * 256 + j]; return; }
    id -= 256 * 512;
    if (id < 40 * 256)   { int j = id >> 8,  c = id & 255;  Wm3T[id] = Wm3[c * 40 + j];  return; }
    id -= 40 * 256;
    if (id < 8 * 6 * 8 * 64 * 8) {
        int j = id & 7;
        int t = id >> 3;
        int lane = t & 63; t >>= 6;
        int f = t & 7; t >>= 3;
        int s = t % 6, nt = t / 6;
        int k = s * 32 + (lane >> 4) * 8 + j;
        int n = nt * 128 + f * 16 + (lane & 15);
        unsigned u = __float_as_uint(Wl[(size_t)k * 1024 + n]);
        u = (u + 0x7FFFu + ((u >> 16) & 1u)) >> 16;
        Wlb[id] = (ushortT)u;
        return;
    }
    id -= 8 * 6 * 8 * 64 * 8;
    if (id < 16384) {
        int mat = id >> 13;
        int rem = id & 8191;
        int part = rem >> 12;
        int t = rem & 4095;
        int frag = t >> 9;
        int r = t & 511;
        int lane = r >> 3, j = r & 7;
        int kf = frag >> 2, nf = frag & 3;
        int k = kf * 32 + (lane >> 4) * 8 + j;
        int n = nf * 16 + (lane & 15);
        float w = (mat ? W1c : W1b)[k * 64 + n];
        _Float16 hi = (_Float16)w;
        Wc1f[id] = part ? (_Float16)(w - (float)hi) : hi;
        return;
    }
}

// ---------------------------------------------------------------------------
// conv1 via split-fp16 MFMA: 1 wave = 16 points, one edge per pass (20 passes).
// ---------------------------------------------------------------------------
__global__ __launch_bounds__(64, 1) void conv1_mfma_kernel(
    const int* __restrict__ idx, const float* __restrict__ u1, const float* __restrict__ v1,
    const _Float16* __restrict__ Wf, const float* __restrict__ b1b, const float* __restrict__ b1c,
    float* __restrict__ x1)
{
    __shared__ int idx_s[16 * 20];
    __shared__ __align__(16) float tr[16 * 68];    // h2 transpose buffer
    __shared__ __align__(16) float xout[16 * 68];  // final x1 staging
    const int lane = threadIdx.x;
    const int row = lane & 15, ks = lane >> 4;
    const int pbase = blockIdx.x * 16;

    for (int t = lane; t < 320; t += 64) idx_s[t] = idx[(size_t)pbase * 20 + t];

    const f16x8* Wp = (const f16x8*)Wf;
    f16x8 wbh[2][4], wbl[2][4], wch[2][4], wcl[2][4];
#pragma unroll
    for (int kf = 0; kf < 2; ++kf)
#pragma unroll
        for (int nf = 0; nf < 4; ++nf) {
            int f = kf * 4 + nf;
            wbh[kf][nf] = Wp[(0 * 8 + f) * 64 + lane];
            wbl[kf][nf] = Wp[(1 * 8 + f) * 64 + lane];
            wch[kf][nf] = Wp[(2 * 8 + f) * 64 + lane];
            wcl[kf][nf] = Wp[(3 * 8 + f) * 64 + lane];
        }
    float bb[4], bc[4];
#pragma unroll
    for (int nf = 0; nf < 4; ++nf) { bb[nf] = b1b[nf * 16 + row]; bc[nf] = b1c[nf * 16 + row]; }

    const int P = pbase + row;
    float4 v1f[4];
    {
        const float4* v4a = (const float4*)(v1 + (size_t)P * 64 + ks * 8);
        v1f[0] = v4a[0]; v1f[1] = v4a[1];
        const float4* v4b = (const float4*)(v1 + (size_t)P * 64 + 32 + ks * 8);
        v1f[2] = v4b[0]; v1f[3] = v4b[1];
    }
    f32x4 xmax[4];
#pragma unroll
    for (int nf = 0; nf < 4; ++nf) xmax[nf] = (f32x4)(-3.0e38f);

    int jn = idx_s[row * 20];
    float4 un[4];
    {
        const float4* up = (const float4*)(u1 + (size_t)jn * 64 + ks * 8);
        un[0] = up[0]; un[1] = up[1];
        const float4* up2 = (const float4*)(u1 + (size_t)jn * 64 + 32 + ks * 8);
        un[2] = up2[0]; un[3] = up2[1];
    }
    for (int e = 0; e < 20; ++e) {
        float4 uc[4] = {un[0], un[1], un[2], un[3]};
        if (e < 19) {
            jn = idx_s[row * 20 + e + 1];
            const float4* up = (const float4*)(u1 + (size_t)jn * 64 + ks * 8);
            un[0] = up[0]; un[1] = up[1];
            const float4* up2 = (const float4*)(u1 + (size_t)jn * 64 + 32 + ks * 8);
            un[2] = up2[0]; un[3] = up2[1];
        }
        f32x4 c2[4];
#pragma unroll
        for (int nf = 0; nf < 4; ++nf) c2[nf] = (f32x4)(bb[nf]);
#pragma unroll
        for (int kf = 0; kf < 2; ++kf) {
            const float* uu = (const float*)&uc[kf * 2];
            const float* vv = (const float*)&v1f[kf * 2];
            f16x8 ah, al;
#pragma unroll
            for (int q = 0; q < 8; ++q) {
                float h = fmaxf(uu[q] + vv[q], 0.f);
                _Float16 hi = (_Float16)h;
                ah[q] = hi;
                al[q] = (_Float16)(h - (float)hi);
            }
#pragma unroll
            for (int nf = 0; nf < 4; ++nf) {
                c2[nf] = __builtin_amdgcn_mfma_f32_16x16x32_f16(ah, wbh[kf][nf], c2[nf], 0, 0, 0);
                c2[nf] = __builtin_amdgcn_mfma_f32_16x16x32_f16(ah, wbl[kf][nf], c2[nf], 0, 0, 0);
                c2[nf] = __builtin_amdgcn_mfma_f32_16x16x32_f16(al, wbh[kf][nf], c2[nf], 0, 0, 0);
            }
        }
#pragma unroll
        for (int nf = 0; nf < 4; ++nf)
#pragma unroll
            for (int r = 0; r < 4; ++r)
                tr[(ks * 4 + r) * 68 + nf * 16 + row] = fmaxf(c2[nf][r], 0.f);
        __builtin_amdgcn_sched_barrier(0);
        f32x4 c3[4];
#pragma unroll
        for (int nf = 0; nf < 4; ++nf) c3[nf] = (f32x4)0.0f;
#pragma unroll
        for (int kf = 0; kf < 2; ++kf) {
            float hbuf[8];
            *(float4*)&hbuf[0] = *(const float4*)&tr[row * 68 + kf * 32 + ks * 8];
            *(float4*)&hbuf[4] = *(const float4*)&tr[row * 68 + kf * 32 + ks * 8 + 4];
            f16x8 ah, al;
#pragma unroll
            for (int q = 0; q < 8; ++q) {
                _Float16 hi = (_Float16)hbuf[q];
                ah[q] = hi;
                al[q] = (_Float16)(hbuf[q] - (float)hi);
            }
#pragma unroll
            for (int nf = 0; nf < 4; ++nf) {
                c3[nf] = __builtin_amdgcn_mfma_f32_16x16x32_f16(ah, wch[kf][nf], c3[nf], 0, 0, 0);
                c3[nf] = __builtin_amdgcn_mfma_f32_16x16x32_f16(ah, wcl[kf][nf], c3[nf], 0, 0, 0);
                c3[nf] = __builtin_amdgcn_mfma_f32_16x16x32_f16(al, wch[kf][nf], c3[nf], 0, 0, 0);
            }
        }
        __builtin_amdgcn_sched_barrier(0);
#pragma unroll
        for (int nf = 0; nf < 4; ++nf) {
            xmax[nf][0] = fmaxf(xmax[nf][0], c3[nf][0]);
            xmax[nf][1] = fmaxf(xmax[nf][1], c3[nf][1]);
            xmax[nf][2] = fmaxf(xmax[nf][2], c3[nf][2]);
            xmax[nf][3] = fmaxf(xmax[nf][3], c3[nf][3]);
        }
    }
#pragma unroll
    for (int nf = 0; nf < 4; ++nf)
#pragma unroll
        for (int r = 0; r < 4; ++r)
            xout[(ks * 4 + r) * 68 + nf * 16 + row] = xmax[nf][r] + bc[nf];
    __builtin_amdgcn_sched_barrier(0);
    {
        const int r2 = lane >> 2, c0 = (lane & 3) * 16;
#pragma unroll
        for (int q = 0; q < 4; ++q) {
            float4 v = *(const float4*)&xout[r2 * 68 + c0 + q * 4];
            *(float4*)(x1 + (size_t)(pbase + r2) * 64 + c0 + q * 4) = v;
        }
    }
}

// ---------------------------------------------------------------------------
// sq norms of x1 rows + Afrag bf16 pack (lin1max) + Xf split-fp16 frags (dist2sel)
// ---------------------------------------------------------------------------
__global__ __launch_bounds__(256) void sqnorm_kernel(
    const float* __restrict__ x1, float* __restrict__ sq,
    ushortT* __restrict__ Afrag, _Float16* __restrict__ Xf)
{
    int i = blockIdx.x * 256 + threadIdx.x;  // 16384
    const float4* r = (const float4*)(x1 + (size_t)i * 64);
    float c[64];
    float s = 0.f;
#pragma unroll
    for (int q = 0; q < 16; ++q) {
        float4 a = r[q];
        c[4 * q] = a.x; c[4 * q + 1] = a.y; c[4 * q + 2] = a.z; c[4 * q + 3] = a.w;
        s += a.x * a.x + a.y * a.y + a.z * a.z + a.w * a.w;
    }
    sq[i] = s;
    const size_t t = i >> 4;
#pragma unroll
    for (int cb = 0; cb < 8; ++cb) {
        uint4 pk;
        pk.x = f2bf_pair(c[8 * cb + 0], c[8 * cb + 1]);
        pk.y = f2bf_pair(c[8 * cb + 2], c[8 * cb + 3]);
        pk.z = f2bf_pair(c[8 * cb + 4], c[8 * cb + 5]);
        pk.w = f2bf_pair(c[8 * cb + 6], c[8 * cb + 7]);
        size_t af = (t * 6 + (cb >> 2)) * 512 + (size_t)((cb & 3) * 16 + (i & 15)) * 8;
        *(uint4*)(Afrag + af) = pk;
        int kf = cb >> 2;
        int lanef = ((cb & 3) << 4) + (i & 15);
        __align__(16) _Float16 hbuf[8];
        __align__(16) _Float16 lbuf[8];
#pragma unroll
        for (int q2 = 0; q2 < 8; ++q2) {
            float v = c[cb * 8 + q2];
            _Float16 hi = (_Float16)v;
            hbuf[q2] = hi;
            lbuf[q2] = (_Float16)(v - (float)hi);
        }
        *(uint4*)(Xf + ((t * 2 + kf) * 2 + 0) * 512 + (size_t)lanef * 8) = *(uint4*)hbuf;
        *(uint4*)(Xf + ((t * 2 + kf) * 2 + 1) * 512 + (size_t)lanef * 8) = *(uint4*)lbuf;
    }
}

// ---------------------------------------------------------------------------
// fused dist2sel v6 (blocks 0..1023) + u2v2 (blocks 1024..1151, 512-thread
// variant: 128-row tile, half = tid>>8 selects column half, A-tile shared in
// LDS; per-thread arithmetic identical to the verified 256-thread u2v2).
// ---------------------------------------------------------------------------
__global__ __launch_bounds__(512, 2) void dist2sel_kernel(
    const _Float16* __restrict__ Xf, const float* __restrict__ sq, int* __restrict__ idx,
    const float* __restrict__ x1, const float* __restrict__ Wcat, const float* __restrict__ b2,
    float* __restrict__ u2, float* __restrict__ v2)
{
    __shared__ unsigned kls[16 * 1024];   // 64 KB (union: u2v2 uses 50.7 KB)
    const int tid = threadIdx.x;

    if (blockIdx.x >= 1024) {
        // ----- u2v2 path -----
        float* aT  = (float*)kls;                       // [32][132]
        const int half = tid >> 8;                      // column half
        float* bW  = (float*)kls + 4224 + half * 4224;  // [32][132] per half
        const int t = tid & 255;
        const int m0 = (blockIdx.x - 1024) << 7;
        const int n0 = half << 7;
        const int ti = t >> 4, tj = t & 15;
        float acc[8][8];
#pragma unroll
        for (int a = 0; a < 8; ++a)
#pragma unroll
            for (int q = 0; q < 8; ++q) acc[a][q] = 0.f;
        for (int ct = 0; ct < 2; ++ct) {
            __syncthreads();
            if (half == 0) {
#pragma unroll
                for (int rep = 0; rep < 4; ++rep) {
                    int f = t + (rep << 8);
                    int r = f >> 3, q = f & 7;
                    float4 v = *(const float4*)(x1 + (size_t)(m0 + r) * 64 + ct * 32 + q * 4);
                    aT[(4 * q + 0) * 132 + r] = v.x; aT[(4 * q + 1) * 132 + r] = v.y;
                    aT[(4 * q + 2) * 132 + r] = v.z; aT[(4 * q + 3) * 132 + r] = v.w;
                }
            }
#pragma unroll
            for (int rep = 0; rep < 4; ++rep) {
                int f = t + (rep << 8);
                int cc = f >> 5, q = f & 31;
                *(float4*)&bW[cc * 132 + 4 * q] =
                    *(const float4*)(Wcat + (size_t)(ct * 32 + cc) * 256 + n0 + q * 4);
            }
            __syncthreads();
#pragma unroll 4
            for (int c = 0; c < 32; ++c) {
                float af[8], bf[8];
                *(float4*)&af[0] = *(const float4*)&aT[c * 132 + ti * 8];
                *(float4*)&af[4] = *(const float4*)&aT[c * 132 + ti * 8 + 4];
                *(float4*)&bf[0] = *(const float4*)&bW[c * 132 + tj * 8];
                *(float4*)&bf[4] = *(const float4*)&bW[c * 132 + tj * 8 + 4];
#pragma unroll
                for (int a = 0; a < 8; ++a)
#pragma unroll
                    for (int q = 0; q < 8; ++q) acc[a][q] = fmaf(af[a], bf[q], acc[a][q]);
            }
        }
#pragma unroll
        for (int a = 0; a < 8; ++a) {
            int m = m0 + ti * 8 + a;
            if (half == 0) {
                float outv[8];
#pragma unroll
                for (int q = 0; q < 8; ++q) outv[q] = acc[a][q];
                *(float4*)(u2 + (size_t)m * 128 + tj * 8)     = *(float4*)&outv[0];
                *(float4*)(u2 + (size_t)m * 128 + tj * 8 + 4) = *(float4*)&outv[4];
            } else {
                float outv[8];
#pragma unroll
                for (int q = 0; q < 8; ++q) outv[q] = acc[a][q] + b2[tj * 8 + q];
                *(float4*)(v2 + (size_t)m * 128 + tj * 8)     = *(float4*)&outv[0];
                *(float4*)(v2 + (size_t)m * 128 + tj * 8 + 4) = *(float4*)&outv[4];
            }
        }
        return;
    }

    // ----- dist2sel path (unchanged from R16/R18) -----
    const int w = tid >> 6, lane = tid & 63;   // w in 0..7
    const int b = blockIdx.x >> 6;
    const int rowtile = blockIdx.x & 63;
    const int c15 = lane & 15;
    const int rbase = (lane >> 4) * 4;

    const f16x8* Xv = (const f16x8*)Xf;
    const int tA = b * 64 + rowtile;
    f16x8 ah[2], al[2];
#pragma unroll
    for (int kf = 0; kf < 2; ++kf) {
        ah[kf] = Xv[((size_t)(tA * 2 + kf) * 2 + 0) * 64 + lane];
        al[kf] = Xv[((size_t)(tA * 2 + kf) * 2 + 1) * 64 + lane];
    }
    const float* sqb = sq + (size_t)b * NP;
    float sqi[4];
#pragma unroll
    for (int rr = 0; rr < 4; ++rr)
        sqi[rr] = sqb[rowtile * 16 + rbase + rr];

    for (int q = 0; q < 8; ++q) {
        const int ct = w * 8 + q;
        const int tB = b * 64 + ct;
        f16x8 bh0 = Xv[((size_t)(tB * 2 + 0) * 2 + 0) * 64 + lane];
        f16x8 bl0 = Xv[((size_t)(tB * 2 + 0) * 2 + 1) * 64 + lane];
        f16x8 bh1 = Xv[((size_t)(tB * 2 + 1) * 2 + 0) * 64 + lane];
        f16x8 bl1 = Xv[((size_t)(tB * 2 + 1) * 2 + 1) * 64 + lane];
        const int col = ct * 16 + c15;
        const float sqj = sqb[col];
        f32x4 acc = (f32x4)0.0f;
        acc = __builtin_amdgcn_mfma_f32_16x16x32_f16(ah[0], bh0, acc, 0, 0, 0);
        acc = __builtin_amdgcn_mfma_f32_16x16x32_f16(ah[0], bl0, acc, 0, 0, 0);
        acc = __builtin_amdgcn_mfma_f32_16x16x32_f16(al[0], bh0, acc, 0, 0, 0);
        acc = __builtin_amdgcn_mfma_f32_16x16x32_f16(ah[1], bh1, acc, 0, 0, 0);
        acc = __builtin_amdgcn_mfma_f32_16x16x32_f16(ah[1], bl1, acc, 0, 0, 0);
        acc = __builtin_amdgcn_mfma_f32_16x16x32_f16(al[1], bh1, acc, 0, 0, 0);
        const int pc = col ^ ((col >> 6) & 15);   // bank swizzle (bijective per 64-col block)
#pragma unroll
        for (int rr = 0; rr < 4; ++rr) {
            float d = sqi[rr] + sqj - 2.0f * acc[rr];
            if (rowtile * 16 + rbase + rr == col) d += 1e10f;
            kls[(rbase + rr) * 1024 + pc] = monokey(d);
        }
    }
    __syncthreads();

    const int gb = b * NP;
    const int r0 = 2 * w, r1 = 2 * w + 1;
    unsigned* hrow0 = &kls[r0 * 1024];
    unsigned* hrow1 = &kls[r1 * 1024];
    unsigned long long perm0 = 0, perm1 = 0;
    {
        unsigned long long key[16];
#pragma unroll
        for (int s = 0; s < 16; ++s) {
            int col = (lane << 4) + s;
            int pc = col ^ ((col >> 6) & 15);
            key[s] = ((unsigned long long)kls[r0 * 1024 + pc] << 32) | (unsigned)col;
        }
        sort16_u64(key);
#pragma unroll
        for (int p = 0; p < 16; ++p) {
            hrow0[p * 64 + lane] = (unsigned)(key[p] >> 32);
            perm0 |= (unsigned long long)((unsigned)key[p] & 15u) << (4 * p);
        }
    }
    {
        unsigned long long key[16];
#pragma unroll
        for (int s = 0; s < 16; ++s) {
            int col = (lane << 4) + s;
            int pc = col ^ ((col >> 6) & 15);
            key[s] = ((unsigned long long)kls[r1 * 1024 + pc] << 32) | (unsigned)col;
        }
        sort16_u64(key);
#pragma unroll
        for (int p = 0; p < 16; ++p) {
            hrow1[p * 64 + lane] = (unsigned)(key[p] >> 32);
            perm1 |= (unsigned long long)((unsigned)key[p] & 15u) << (4 * p);
        }
    }
    dual_tourney20(hrow0, perm0, hrow1, perm1, lane,
                   idx + (size_t)(gb + rowtile * 16 + r0) * KNB,
                   idx + (size_t)(gb + rowtile * 16 + r1) * KNB, gb);
}

// ---------------------------------------------------------------------------
// conv2 gather-max -> Afrag k=64..191 (bf16 fragment layout), x2 never stored
// ---------------------------------------------------------------------------
__global__ __launch_bounds__(256) void gatherfrag_kernel(
    const int* __restrict__ idx, const float* __restrict__ u2,
    const float* __restrict__ v2, ushortT* __restrict__ Afrag)
{
    const int tid = threadIdx.x;
    const int i = blockIdx.x * 16 + (tid >> 4);
    const int cb = tid & 15;
    const int* ib = idx + (size_t)i * KNB;
    float m[8];
#pragma unroll
    for (int d = 0; d < 8; ++d) m[d] = -3e38f;
    for (int e = 0; e < KNB; ++e) {
        int j = ib[e];
        const float4* p = (const float4*)(u2 + (size_t)j * 128 + cb * 8);
        float4 a = p[0], b = p[1];
        m[0] = fmaxf(m[0], a.x); m[1] = fmaxf(m[1], a.y); m[2] = fmaxf(m[2], a.z); m[3] = fmaxf(m[3], a.w);
        m[4] = fmaxf(m[4], b.x); m[5] = fmaxf(m[5], b.y); m[6] = fmaxf(m[6], b.z); m[7] = fmaxf(m[7], b.w);
    }
    const float4* vp = (const float4*)(v2 + (size_t)i * 128 + cb * 8);
    float4 va = vp[0], vb = vp[1];
    m[0] += va.x; m[1] += va.y; m[2] += va.z; m[3] += va.w;
    m[4] += vb.x; m[5] += vb.y; m[6] += vb.z; m[7] += vb.w;
    uint4 pk;
    pk.x = f2bf_pair(m[0], m[1]);
    pk.y = f2bf_pair(m[2], m[3]);
    pk.z = f2bf_pair(m[4], m[5]);
    pk.w = f2bf_pair(m[6], m[7]);
    size_t af = ((size_t)(i >> 4) * 6 + 2 + (cb >> 2)) * 512 + (size_t)((cb & 3) * 16 + (i & 15)) * 8;
    *(uint4*)(Afrag + af) = pk;
}

// ---------------------------------------------------------------------------
// lin1 + global max pool via bf16 MFMA.
// ---------------------------------------------------------------------------
__global__ __launch_bounds__(256) void lin1max_mfma_kernel(
    const ushortT* __restrict__ Afrag, const ushortT* __restrict__ Wlb, float* __restrict__ gp)
{
    __shared__ float red[4][128];
    const int tid = threadIdx.x;
    const int w = tid >> 6, lane = tid & 63;
    const int nt = blockIdx.x & 7;
    const int rt = (blockIdx.x >> 3) & 7;
    const int b  = blockIdx.x >> 6;
    const int rt16 = ((b << 3) + rt) * 8 + (w << 1);
    const bf16x8* Ap = (const bf16x8*)Afrag;
    const bf16x8* Bp = (const bf16x8*)Wlb;
    f32x4 acc[2][8];
#pragma unroll
    for (int mm = 0; mm < 2; ++mm)
#pragma unroll
        for (int f = 0; f < 8; ++f) acc[mm][f] = (f32x4)0.0f;
#pragma unroll
    for (int s = 0; s < 6; ++s) {
        bf16x8 a0 = Ap[((rt16    ) * 6 + s) * 64 + lane];
        bf16x8 a1 = Ap[((rt16 + 1) * 6 + s) * 64 + lane];
#pragma unroll
        for (int f = 0; f < 8; ++f) {
            bf16x8 bb = Bp[(((nt * 6 + s) << 3) + f) * 64 + lane];
            acc[0][f] = __builtin_amdgcn_mfma_f32_16x16x32_bf16(a0, bb, acc[0][f], 0, 0, 0);
            acc[1][f] = __builtin_amdgcn_mfma_f32_16x16x32_bf16(a1, bb, acc[1][f], 0, 0, 0);
        }
    }
#pragma unroll
    for (int f = 0; f < 8; ++f) {
        float m = acc[0][f][0];
        m = fmaxf(m, acc[0][f][1]); m = fmaxf(m, acc[0][f][2]); m = fmaxf(m, acc[0][f][3]);
        m = fmaxf(m, acc[1][f][0]); m = fmaxf(m, acc[1][f][1]);
        m = fmaxf(m, acc[1][f][2]); m = fmaxf(m, acc[1][f][3]);
        m = fmaxf(m, __shfl_xor(m, 16, 64));
        m = fmaxf(m, __shfl_xor(m, 32, 64));
        if (lane < 16) red[w][f * 16 + lane] = m;
    }
    __syncthreads();
    if (tid < 128) {
        float m = fmaxf(fmaxf(red[0][tid], red[1][tid]), fmaxf(red[2][tid], red[3][tid]));
        gp[((size_t)rt * NB + b) * 1024 + nt * 128 + tid] = m;
    }
}

// ---------------------------------------------------------------------------
// head stage 0: gs[b][c] = max over 8 gp parts + bl[c]   (16x1024)
// ---------------------------------------------------------------------------
__global__ __launch_bounds__(256) void gmax_kernel(
    const float* __restrict__ gp, const float* __restrict__ bl, float* __restrict__ gs)
{
    int id = blockIdx.x * 256 + threadIdx.x;   // 16384
    int b = id >> 10, c = id & 1023;
    float m = gp[(size_t)b * 1024 + c];
#pragma unroll
    for (int part = 1; part < 8; ++part)
        m = fmaxf(m, gp[((size_t)part * NB + b) * 1024 + c]);
    gs[(size_t)b * 1024 + c] = m + bl[c];
}

// ---------------------------------------------------------------------------
// head stage 1: h1[b][j] = relu(gs[b] . Wm1T[j] + bm1[j]); one block per j.
// ---------------------------------------------------------------------------
__global__ __launch_bounds__(256) void head1_kernel(
    const float* __restrict__ gs, const float* __restrict__ Wm1T, const float* __restrict__ bm1,
    float* __restrict__ h1)
{
    __shared__ float red[16][17];
    const int j = blockIdx.x;                  // 0..511
    const int t = threadIdx.x;
    const int b = t >> 4, seg = t & 15;
    const float4* wr = (const float4*)(Wm1T + (size_t)j * 1024 + seg * 64);
    const float4* gr = (const float4*)(gs + (size_t)b * 1024 + seg * 64);
    float acc = 0.f;
#pragma unroll
    for (int q = 0; q < 16; ++q) {
        float4 w = wr[q], g = gr[q];
        acc = fmaf(w.x, g.x, acc); acc = fmaf(w.y, g.y, acc);
        acc = fmaf(w.z, g.z, acc); acc = fmaf(w.w, g.w, acc);
    }
    red[b][seg] = acc;
    __syncthreads();
    if (t < 16) {
        float s = 0.f;
#pragma unroll
        for (int k = 0; k < 16; ++k) s += red[t][k];
        h1[(size_t)t * 512 + j] = fmaxf(s + bm1[j], 0.f);
    }
}

// ---------------------------------------------------------------------------
// head stage 2: h2[b][j] = relu(h1[b] . Wm2T[j] + bm2[j]); one block per j.
// ---------------------------------------------------------------------------
__global__ __launch_bounds__(256) void head2_kernel(
    const float* __restrict__ h1, const float* __restrict__ Wm2T, const float* __restrict__ bm2,
    float* __restrict__ h2)
{
    __shared__ float red[16][17];
    const int j = blockIdx.x;                  // 0..255
    const int t = threadIdx.x;
    const int b = t >> 4, seg = t & 15;
    const float4* wr = (const float4*)(Wm2T + (size_t)j * 512 + seg * 32);
    const float4* hr = (const float4*)(h1 + (size_t)b * 512 + seg * 32);
    float acc = 0.f;
#pragma unroll
    for (int q = 0; q < 8; ++q) {
        float4 w = wr[q], g = hr[q];
        acc = fmaf(w.x, g.x, acc); acc = fmaf(w.y, g.y, acc);
        acc = fmaf(w.z, g.z, acc); acc = fmaf(w.w, g.w, acc);
    }
    red[b][seg] = acc;
    __syncthreads();
    if (t < 16) {
        float s = 0.f;
#pragma unroll
        for (int k = 0; k < 16; ++k) s += red[t][k];
        h2[(size_t)t * 256 + j] = fmaxf(s + bm2[j], 0.f);
    }
}

// ---------------------------------------------------------------------------
// head stage 3: logits + log_softmax; one block per batch.
// ---------------------------------------------------------------------------
__global__ __launch_bounds__(256) void head3_kernel(
    const float* __restrict__ h2, const float* __restrict__ Wm3T, const float* __restrict__ bm3,
    float* __restrict__ out)
{
    __shared__ float lg[64];
    const int tid = threadIdx.x;
    const int b = blockIdx.x;
    if (tid < 40) {
        float acc = bm3[tid];
        const float4* wr = (const float4*)(Wm3T + (size_t)tid * 256);
        const float4* hr = (const float4*)(h2 + (size_t)b * 256);
#pragma unroll
        for (int c4 = 0; c4 < 64; ++c4) {
            float4 w = wr[c4];
            float4 g4 = hr[c4];
            acc = fmaf(w.x, g4.x, acc); acc = fmaf(w.y, g4.y, acc);
            acc = fmaf(w.z, g4.z, acc); acc = fmaf(w.w, g4.w, acc);
        }
        lg[tid] = acc;
    }
    __syncthreads();
    if (tid < 64) {
        float v = (tid < 40) ? lg[tid] : -3e38f;
        float m = v;
        for (int off = 32; off; off >>= 1) m = fmaxf(m, __shfl_xor(m, off, 64));
        float ex = (tid < 40) ? expf(v - m) : 0.f;
        float s = ex;
        for (int off = 32; off; off >>= 1) s += __shfl_xor(s, off, 64);
        if (tid < 40) out[b * 40 + tid] = v - m - logf(s);
    }
}

// ---------------------------------------------------------------------------
extern "C" void kernel_launch(void* const* d_in, const int* in_sizes, int n_in,
                              void* d_out, int out_size, void* d_ws, size_t ws_size,
                              hipStream_t stream)
{
    const float* pos = (const float*)d_in[0];
    const float* W1a = (const float*)d_in[1];
    const float* b1a = (const float*)d_in[2];
    const float* W1b = (const float*)d_in[3];
    const float* b1b = (const float*)d_in[4];
    const float* W1c = (const float*)d_in[5];
    const float* b1c = (const float*)d_in[6];
    const float* W2  = (const float*)d_in[7];
    const float* b2  = (const float*)d_in[8];
    const float* Wl  = (const float*)d_in[9];
    const float* bl  = (const float*)d_in[10];
    const float* Wm1 = (const float*)d_in[11];
    const float* bm1 = (const float*)d_in[12];
    const float* Wm2 = (const float*)d_in[13];
    const float* bm2 = (const float*)d_in[14];
    const float* Wm3 = (const float*)d_in[15];
    const float* bm3 = (const float*)d_in[16];
    float* out = (float*)d_out;

    char* ws = (char*)d_ws;
    const size_t MB = 1024 * 1024;
    size_t off = 0;
    auto alloc = [&](size_t bytes) { size_t o = off; off += (bytes + 255) & ~(size_t)255; return o; };
    size_t u2_off  = alloc(8 * MB);          // u1 (4MB) then u2 (8MB)
    size_t v2_off  = alloc(8 * MB);          // v1 (4MB) then v2 (8MB)
    size_t x1_off  = alloc(4 * MB);
    size_t idx_off = alloc((size_t)NPT * KNB * 4);
    size_t sq_off  = alloc((size_t)NPT * 4);
    size_t gp_off  = alloc((size_t)8 * NB * 1024 * 4);
    size_t gs_off  = alloc((size_t)NB * 1024 * 4);
    size_t h1_off  = alloc((size_t)NB * 512 * 4);
    size_t h2_off  = alloc((size_t)NB * 256 * 4);
    size_t wc_off  = alloc(64 * 256 * 4);
    size_t w1t_off = alloc(512 * 1024 * 4);
    size_t w2t_off = alloc(256 * 512 * 4);
    size_t w3t_off = alloc(40 * 256 * 4);
    size_t af_off  = alloc((size_t)(NPT / 16) * 6 * 512 * 2);  // 6 MB bf16 A-fragments
    size_t wlb_off = alloc((size_t)8 * 6 * 8 * 512 * 2);       // 384 KB bf16 Wl fragments
    size_t wcf_off = alloc((size_t)16384 * 2);                 // 32 KB split-fp16 conv1 W frags
    size_t xf_off  = alloc((size_t)(NPT / 16) * 2 * 2 * 512 * 2); // 4 MB split-fp16 x1 frags
    if (ws_size < off) { fail_kernel<<<3, 256, 0, stream>>>(out, out_size); return; }

    float* u1    = (float*)(ws + u2_off);
    float* v1    = (float*)(ws + v2_off);
    float* u2    = (float*)(ws + u2_off);
    float* v2    = (float*)(ws + v2_off);
    float* x1    = (float*)(ws + x1_off);
    int*   idx   = (int*)(ws + idx_off);
    float* sq    = (float*)(ws + sq_off);
    float* gp    = (float*)(ws + gp_off);
    float* gs    = (float*)(ws + gs_off);
    float* h1    = (float*)(ws + h1_off);
    float* h2    = (float*)(ws + h2_off);
    float* Wcat  = (float*)(ws + wc_off);
    float* Wm1T  = (float*)(ws + w1t_off);
    float* Wm2T  = (float*)(ws + w2t_off);
    float* Wm3T  = (float*)(ws + w3t_off);
    ushortT* Afrag = (ushortT*)(ws + af_off);
    ushortT* Wlb   = (ushortT*)(ws + wlb_off);
    _Float16* Wc1f = (_Float16*)(ws + wcf_off);
    _Float16* Xf   = (_Float16*)(ws + xf_off);

    phase1_kernel<<<11688, 256, 0, stream>>>(pos, W1a, b1a, W2, Wm1, Wm2, Wm3, Wl, W1b, W1c,
                                             idx, u1, v1, Wcat, Wm1T, Wm2T, Wm3T, Wlb, Wc1f);
    conv1_mfma_kernel<<<1024, 64, 0, stream>>>(idx, u1, v1, Wc1f, b1b, b1c, x1);
    sqnorm_kernel<<<64, 256, 0, stream>>>(x1, sq, Afrag, Xf);
    dist2sel_kernel<<<1152, 512, 0, stream>>>(Xf, sq, idx, x1, Wcat, b2, u2, v2);
    gatherfrag_kernel<<<1024, 256, 0, stream>>>(idx, u2, v2, Afrag);
    lin1max_mfma_kernel<<<1024, 256, 0, stream>>>(Afrag, Wlb, gp);
    gmax_kernel<<<64, 256, 0, stream>>>(gp, bl, gs);
    head1_kernel<<<512, 256, 0, stream>>>(gs, Wm1T, bm1, h1);
    head2_kernel<<<256, 256, 0, stream>>>(h1, Wm2T, bm2, h2);
    head3_kernel<<<16, 256, 0, stream>>>(h2, Wm3T, bm3, out);
}

// Round 20
// 182.819 us; speedup vs baseline: 1.0757x; 1.0168x over previous
//
#include <hip/hip_runtime.h>

constexpr int NB  = 16;      // batches
constexpr int NP  = 1024;    // points per batch
constexpr int NPT = NB * NP; // 16384
constexpr int KNB = 20;

typedef unsigned short ushortT;
typedef __bf16 bf16x8 __attribute__((ext_vector_type(8)));
typedef _Float16 f16x8 __attribute__((ext_vector_type(8)));
typedef float f32x4 __attribute__((ext_vector_type(4)));

__device__ inline unsigned f2bf_pair(float f0, float f1) {
    unsigned u0 = __float_as_uint(f0); u0 = (u0 + 0x7FFFu + ((u0 >> 16) & 1u)) >> 16;
    unsigned u1 = __float_as_uint(f1); u1 = (u1 + 0x7FFFu + ((u1 >> 16) & 1u)) >> 16;
    return u0 | (u1 << 16);
}

// monotone uint32 transform: u < v  <=>  f < g
__device__ inline unsigned monokey(float f) {
    unsigned u = __float_as_uint(f);
    return u ^ ((unsigned)((int)u >> 31) | 0x80000000u);
}

// min over each 16-lane row via DPP (VALU-latency cross-lane, no DS pipe)
__device__ inline unsigned dppmin16(unsigned v) {
    unsigned t;
    t = (unsigned)__builtin_amdgcn_update_dpp((int)v, (int)v, 0xB1, 0xF, 0xF, false);  // quad [1,0,3,2]
    v = v < t ? v : t;
    t = (unsigned)__builtin_amdgcn_update_dpp((int)v, (int)v, 0x4E, 0xF, 0xF, false);  // quad [2,3,0,1]
    v = v < t ? v : t;
    t = (unsigned)__builtin_amdgcn_update_dpp((int)v, (int)v, 0x141, 0xF, 0xF, false); // row_half_mirror
    v = v < t ? v : t;
    t = (unsigned)__builtin_amdgcn_update_dpp((int)v, (int)v, 0x140, 0xF, 0xF, false); // row_mirror
    v = v < t ? v : t;
    return v;
}

// ---------------------------------------------------------------------------
// bitonic sort of 16 u64 keys, ascending (validated bit-exact in round 4)
// ---------------------------------------------------------------------------
__device__ inline void sort16_u64(unsigned long long key[16]) {
#pragma unroll
    for (int k = 2; k <= 16; k <<= 1) {
#pragma unroll
        for (int j = k >> 1; j > 0; j >>= 1) {
#pragma unroll
            for (int a = 0; a < 16; ++a) {
                int b = a ^ j;
                if (b > a) {
                    unsigned long long x = key[a], y = key[b];
                    bool lt = x < y;
                    unsigned long long mn = lt ? x : y, mx = lt ? y : x;
                    if ((a & k) == 0) { key[a] = mn; key[b] = mx; }
                    else              { key[a] = mx; key[b] = mn; }
                }
            }
        }
    }
}

// ---------------------------------------------------------------------------
// wave-wide top-20 via sorted per-lane runs + LDS-head tournament
// (knn3 variant, R12-proven: private 17-entry u64 column, sentinel at [16]).
// ---------------------------------------------------------------------------
__device__ inline void wave_top20_lds(unsigned long long key[16], int lane,
                                      unsigned long long* __restrict__ col,
                                      int* __restrict__ outp, int jadd)
{
    sort16_u64(key);
#pragma unroll
    for (int s = 0; s < 16; ++s) col[s] = key[s];
    unsigned ptr = 0;
    for (int t = 0; t < KNB; ++t) {
        unsigned long long h = col[ptr];     // ds_read_b64, per-wave in-order
        unsigned hv = (unsigned)(h >> 32);
        unsigned hj = (unsigned)h;
        unsigned r = dppmin16(hv);
        unsigned g0 = (unsigned)__builtin_amdgcn_readlane((int)r, 0);
        unsigned g1 = (unsigned)__builtin_amdgcn_readlane((int)r, 16);
        unsigned g2 = (unsigned)__builtin_amdgcn_readlane((int)r, 32);
        unsigned g3 = (unsigned)__builtin_amdgcn_readlane((int)r, 48);
        unsigned g = min(min(g0, g1), min(g2, g3));     // uniform (SGPR)
        unsigned long long ball = __ballot(hv == g);
        int wl = __ffsll(ball) - 1;                      // lowest lane = lowest j
        int wj = __builtin_amdgcn_readlane((int)hj, wl);
        if (lane == 0) outp[t] = jadd + wj;
        ptr += (lane == wl) ? 1u : 0u;                   // branchless advance
    }
}

// ---------------------------------------------------------------------------
// interleaved dual-row tournament (R16-proven)
// ---------------------------------------------------------------------------
__device__ inline void dual_tourney20(
    unsigned* __restrict__ hrow0, unsigned long long perm0,
    unsigned* __restrict__ hrow1, unsigned long long perm1,
    int lane, int* __restrict__ outA, int* __restrict__ outB, int jadd)
{
    unsigned ptrA = 0, ptrB = 0;
    unsigned curA = hrow0[lane], nxtA = hrow0[64 + lane];
    unsigned curB = hrow1[lane], nxtB = hrow1[64 + lane];
    unsigned csA = (unsigned)(perm0 & 15ull), nsA = (unsigned)((perm0 >> 4) & 15ull);
    unsigned csB = (unsigned)(perm1 & 15ull), nsB = (unsigned)((perm1 >> 4) & 15ull);
    for (int t = 0; t < KNB; ++t) {
        unsigned rmA = dppmin16(curA);
        unsigned rmB = dppmin16(curB);
        unsigned a0 = (unsigned)__builtin_amdgcn_readlane((int)rmA, 0);
        unsigned b0 = (unsigned)__builtin_amdgcn_readlane((int)rmB, 0);
        unsigned a1 = (unsigned)__builtin_amdgcn_readlane((int)rmA, 16);
        unsigned b1 = (unsigned)__builtin_amdgcn_readlane((int)rmB, 16);
        unsigned a2 = (unsigned)__builtin_amdgcn_readlane((int)rmA, 32);
        unsigned b2 = (unsigned)__builtin_amdgcn_readlane((int)rmB, 32);
        unsigned a3 = (unsigned)__builtin_amdgcn_readlane((int)rmA, 48);
        unsigned b3 = (unsigned)__builtin_amdgcn_readlane((int)rmB, 48);
        unsigned gA = min(min(a0, a1), min(a2, a3));
        unsigned gB = min(min(b0, b1), min(b2, b3));
        unsigned long long ballA = __ballot(curA == gA);
        unsigned long long ballB = __ballot(curB == gB);
        int wlA = __ffsll(ballA) - 1;
        int wlB = __ffsll(ballB) - 1;
        int jA = (lane << 4) + (int)csA;
        int jB = (lane << 4) + (int)csB;
        int wjA = __builtin_amdgcn_readlane(jA, wlA);
        int wjB = __builtin_amdgcn_readlane(jB, wlB);
        if (lane == 0) { outA[t] = jadd + wjA; outB[t] = jadd + wjB; }
        if (lane == wlA) {
            curA = nxtA; csA = nsA;
            ptrA += 1u;
            unsigned p2 = ptrA + 1u;
            unsigned p2c = p2 < 15u ? p2 : 15u;
            nsA = (unsigned)((perm0 >> (4 * (int)p2c)) & 15ull);
            nxtA = (p2 < 16u) ? hrow0[p2 * 64 + lane] : 0xFFFFFFFFu;
        }
        if (lane == wlB) {
            curB = nxtB; csB = nsB;
            ptrB += 1u;
            unsigned p2 = ptrB + 1u;
            unsigned p2c = p2 < 15u ? p2 : 15u;
            nsB = (unsigned)((perm1 >> (4 * (int)p2c)) & 15ull);
            nxtB = (p2 < 16u) ? hrow1[p2 * 64 + lane] : 0xFFFFFFFFu;
        }
    }
}

// ---------------------------------------------------------------------------
__global__ void fail_kernel(float* out, int n) {
    int i = blockIdx.x * 256 + threadIdx.x;
    if (i < n) out[i] = -777.0f;
}

// ---------------------------------------------------------------------------
// phase1 (R12-proven): fused knn3 (blocks 0..4095, 1 row/wave) +
// prep_uv1 (4096..8191) + prep_w (rest). knn3 heap = 34 KB u64 w/ sentinel.
// ---------------------------------------------------------------------------
__global__ __launch_bounds__(256) void phase1_kernel(
    const float* __restrict__ pos, const float* __restrict__ W1a, const float* __restrict__ b1a,
    const float* __restrict__ W2,
    const float* __restrict__ Wm1, const float* __restrict__ Wm2, const float* __restrict__ Wm3,
    const float* __restrict__ Wl, const float* __restrict__ W1b, const float* __restrict__ W1c,
    int* __restrict__ idx, float* __restrict__ u1, float* __restrict__ v1,
    float* __restrict__ Wcat, float* __restrict__ Wm1T, float* __restrict__ Wm2T, float* __restrict__ Wm3T,
    ushortT* __restrict__ Wlb, _Float16* __restrict__ Wc1f)
{
    __shared__ unsigned long long heap[4][64][17];
    const int bid = blockIdx.x;
    const int tid = threadIdx.x;
    if (bid < 4096) {
        const int w = tid >> 6, lane = tid & 63;
        const int b = bid >> 8;
        const int i = ((bid & 255) << 2) + w;
        const float* pb = pos + (size_t)b * NP * 3;
        float cbuf[48];
        {
            const float4* src = (const float4*)(pb + lane * 48);
#pragma unroll
            for (int q = 0; q < 12; ++q) *(float4*)&cbuf[q * 4] = src[q];
        }
        const float xi = pb[3 * i], yi = pb[3 * i + 1], zi = pb[3 * i + 2];
        const float sqi = xi * xi + yi * yi + zi * zi;
        unsigned long long key[16];
#pragma unroll
        for (int s = 0; s < 16; ++s) {
            float x = cbuf[3 * s], y = cbuf[3 * s + 1], z = cbuf[3 * s + 2];
            float d = sqi + (x * x + y * y + z * z) - 2.0f * (xi * x + yi * y + zi * z);
            int j = (lane << 4) + s;
            if (j == i) d += 1e10f;
            key[s] = ((unsigned long long)monokey(d) << 32) | (unsigned)j;
        }
        heap[w][lane][16] = ~0ULL;   // sentinel
        wave_top20_lds(key, lane, &heap[w][lane][0], idx + (size_t)(b * NP + i) * KNB, b * NP);
        return;
    }
    if (bid < 8192) {
        int id = (bid - 4096) * 256 + tid;  // 16384*64
        int i = id >> 6, c = id & 63;
        float x = pos[3 * i], y = pos[3 * i + 1], z = pos[3 * i + 2];
        float wu0 = W1a[3 * 64 + c], wu1 = W1a[4 * 64 + c], wu2 = W1a[5 * 64 + c];
        float wv0 = W1a[0 * 64 + c] - wu0, wv1 = W1a[1 * 64 + c] - wu1, wv2 = W1a[2 * 64 + c] - wu2;
        u1[id] = x * wu0 + y * wu1 + z * wu2;
        v1[id] = b1a[c] + x * wv0 + y * wv1 + z * wv2;
        return;
    }
    int id = (bid - 8192) * 256 + tid;
    if (id < 64 * 256) {
        int c = id >> 8, n = id & 255;
        float wb = W2[(64 + c) * 128 + (n & 127)];
        Wcat[id] = (n < 128) ? wb : (W2[c * 128 + (n - 128)] - wb);
        return;
    }
    id -= 64 * 256;
    if (id < 512 * 1024) { int j = id >> 10, c = id & 1023; Wm1T[id] = Wm1[c * 512 + j]; return; }
    id -= 512 * 1024;
    if (id < 256 * 512)  { int j = id >> 9,  c = id & 511;  Wm2T[id] = Wm2[c * 256 + j]; return; }
    id -= 256 * 512;
    if (id < 40 * 256)   { int j = id >> 8,  c = id & 255;  Wm3T[id] = Wm3[c * 40 + j];  return; }
    id -= 40 * 256;
    if (id < 8 * 6 * 8 * 64 * 8) {
        int j = id & 7;
        int t = id >> 3;
        int lane = t & 63; t >>= 6;
        int f = t & 7; t >>= 3;
        int s = t % 6, nt = t / 6;
        int k = s * 32 + (lane >> 4) * 8 + j;
        int n = nt * 128 + f * 16 + (lane & 15);
        unsigned u = __float_as_uint(Wl[(size_t)k * 1024 + n]);
        u = (u + 0x7FFFu + ((u >> 16) & 1u)) >> 16;
        Wlb[id] = (ushortT)u;
        return;
    }
    id -= 8 * 6 * 8 * 64 * 8;
    if (id < 16384) {
        int mat = id >> 13;
        int rem = id & 8191;
        int part = rem >> 12;
        int t = rem & 4095;
        int frag = t >> 9;
        int r = t & 511;
        int lane = r >> 3, j = r & 7;
        int kf = frag >> 2, nf = frag & 3;
        int k = kf * 32 + (lane >> 4) * 8 + j;
        int n = nf * 16 + (lane & 15);
        float w = (mat ? W1c : W1b)[k * 64 + n];
        _Float16 hi = (_Float16)w;
        Wc1f[id] = part ? (_Float16)(w - (float)hi) : hi;
        return;
    }
}

// ---------------------------------------------------------------------------
// conv1 via split-fp16 MFMA + fused sqnorm/Afrag(k0-63)/Xf epilogue
// (bit-identical to the old separate sqnorm kernel: same xout values, same
// pack formulas; sq via 4-lane quad shfl_xor reduce).
// ---------------------------------------------------------------------------
__global__ __launch_bounds__(64, 1) void conv1_mfma_kernel(
    const int* __restrict__ idx, const float* __restrict__ u1, const float* __restrict__ v1,
    const _Float16* __restrict__ Wf, const float* __restrict__ b1b, const float* __restrict__ b1c,
    float* __restrict__ x1, float* __restrict__ sq,
    ushortT* __restrict__ Afrag, _Float16* __restrict__ Xf)
{
    __shared__ int idx_s[16 * 20];
    __shared__ __align__(16) float tr[16 * 68];    // h2 transpose buffer
    __shared__ __align__(16) float xout[16 * 68];  // final x1 staging
    const int lane = threadIdx.x;
    const int row = lane & 15, ks = lane >> 4;
    const int pbase = blockIdx.x * 16;

    for (int t = lane; t < 320; t += 64) idx_s[t] = idx[(size_t)pbase * 20 + t];

    const f16x8* Wp = (const f16x8*)Wf;
    f16x8 wbh[2][4], wbl[2][4], wch[2][4], wcl[2][4];
#pragma unroll
    for (int kf = 0; kf < 2; ++kf)
#pragma unroll
        for (int nf = 0; nf < 4; ++nf) {
            int f = kf * 4 + nf;
            wbh[kf][nf] = Wp[(0 * 8 + f) * 64 + lane];
            wbl[kf][nf] = Wp[(1 * 8 + f) * 64 + lane];
            wch[kf][nf] = Wp[(2 * 8 + f) * 64 + lane];
            wcl[kf][nf] = Wp[(3 * 8 + f) * 64 + lane];
        }
    float bb[4], bc[4];
#pragma unroll
    for (int nf = 0; nf < 4; ++nf) { bb[nf] = b1b[nf * 16 + row]; bc[nf] = b1c[nf * 16 + row]; }

    const int P = pbase + row;
    float4 v1f[4];
    {
        const float4* v4a = (const float4*)(v1 + (size_t)P * 64 + ks * 8);
        v1f[0] = v4a[0]; v1f[1] = v4a[1];
        const float4* v4b = (const float4*)(v1 + (size_t)P * 64 + 32 + ks * 8);
        v1f[2] = v4b[0]; v1f[3] = v4b[1];
    }
    f32x4 xmax[4];
#pragma unroll
    for (int nf = 0; nf < 4; ++nf) xmax[nf] = (f32x4)(-3.0e38f);

    int jn = idx_s[row * 20];
    float4 un[4];
    {
        const float4* up = (const float4*)(u1 + (size_t)jn * 64 + ks * 8);
        un[0] = up[0]; un[1] = up[1];
        const float4* up2 = (const float4*)(u1 + (size_t)jn * 64 + 32 + ks * 8);
        un[2] = up2[0]; un[3] = up2[1];
    }
    for (int e = 0; e < 20; ++e) {
        float4 uc[4] = {un[0], un[1], un[2], un[3]};
        if (e < 19) {
            jn = idx_s[row * 20 + e + 1];
            const float4* up = (const float4*)(u1 + (size_t)jn * 64 + ks * 8);
            un[0] = up[0]; un[1] = up[1];
            const float4* up2 = (const float4*)(u1 + (size_t)jn * 64 + 32 + ks * 8);
            un[2] = up2[0]; un[3] = up2[1];
        }
        f32x4 c2[4];
#pragma unroll
        for (int nf = 0; nf < 4; ++nf) c2[nf] = (f32x4)(bb[nf]);
#pragma unroll
        for (int kf = 0; kf < 2; ++kf) {
            const float* uu = (const float*)&uc[kf * 2];
            const float* vv = (const float*)&v1f[kf * 2];
            f16x8 ah, al;
#pragma unroll
            for (int q = 0; q < 8; ++q) {
                float h = fmaxf(uu[q] + vv[q], 0.f);
                _Float16 hi = (_Float16)h;
                ah[q] = hi;
                al[q] = (_Float16)(h - (float)hi);
            }
#pragma unroll
            for (int nf = 0; nf < 4; ++nf) {
                c2[nf] = __builtin_amdgcn_mfma_f32_16x16x32_f16(ah, wbh[kf][nf], c2[nf], 0, 0, 0);
                c2[nf] = __builtin_amdgcn_mfma_f32_16x16x32_f16(ah, wbl[kf][nf], c2[nf], 0, 0, 0);
                c2[nf] = __builtin_amdgcn_mfma_f32_16x16x32_f16(al, wbh[kf][nf], c2[nf], 0, 0, 0);
            }
        }
#pragma unroll
        for (int nf = 0; nf < 4; ++nf)
#pragma unroll
            for (int r = 0; r < 4; ++r)
                tr[(ks * 4 + r) * 68 + nf * 16 + row] = fmaxf(c2[nf][r], 0.f);
        __builtin_amdgcn_sched_barrier(0);
        f32x4 c3[4];
#pragma unroll
        for (int nf = 0; nf < 4; ++nf) c3[nf] = (f32x4)0.0f;
#pragma unroll
        for (int kf = 0; kf < 2; ++kf) {
            float hbuf[8];
            *(float4*)&hbuf[0] = *(const float4*)&tr[row * 68 + kf * 32 + ks * 8];
            *(float4*)&hbuf[4] = *(const float4*)&tr[row * 68 + kf * 32 + ks * 8 + 4];
            f16x8 ah, al;
#pragma unroll
            for (int q = 0; q < 8; ++q) {
                _Float16 hi = (_Float16)hbuf[q];
                ah[q] = hi;
                al[q] = (_Float16)(hbuf[q] - (float)hi);
            }
#pragma unroll
            for (int nf = 0; nf < 4; ++nf) {
                c3[nf] = __builtin_amdgcn_mfma_f32_16x16x32_f16(ah, wch[kf][nf], c3[nf], 0, 0, 0);
                c3[nf] = __builtin_amdgcn_mfma_f32_16x16x32_f16(ah, wcl[kf][nf], c3[nf], 0, 0, 0);
                c3[nf] = __builtin_amdgcn_mfma_f32_16x16x32_f16(al, wch[kf][nf], c3[nf], 0, 0, 0);
            }
        }
        __builtin_amdgcn_sched_barrier(0);
#pragma unroll
        for (int nf = 0; nf < 4; ++nf) {
            xmax[nf][0] = fmaxf(xmax[nf][0], c3[nf][0]);
            xmax[nf][1] = fmaxf(xmax[nf][1], c3[nf][1]);
            xmax[nf][2] = fmaxf(xmax[nf][2], c3[nf][2]);
            xmax[nf][3] = fmaxf(xmax[nf][3], c3[nf][3]);
        }
    }
#pragma unroll
    for (int nf = 0; nf < 4; ++nf)
#pragma unroll
        for (int r = 0; r < 4; ++r)
            xout[(ks * 4 + r) * 68 + nf * 16 + row] = xmax[nf][r] + bc[nf];
    __builtin_amdgcn_sched_barrier(0);
    {
        const int r2 = lane >> 2, part = lane & 3, c0 = part * 16;
        const int g2 = pbase + r2;
        float ch[16];
#pragma unroll
        for (int q = 0; q < 4; ++q) {
            float4 v = *(const float4*)&xout[r2 * 68 + c0 + q * 4];
            *(float4*)(x1 + (size_t)g2 * 64 + c0 + q * 4) = v;
            ch[4 * q + 0] = v.x; ch[4 * q + 1] = v.y;
            ch[4 * q + 2] = v.z; ch[4 * q + 3] = v.w;
        }
        // sq: partial over 16 channels, quad reduce (lane = 4*r2 + part)
        float s = 0.f;
#pragma unroll
        for (int q = 0; q < 16; ++q) s += ch[q] * ch[q];
        s += __shfl_xor(s, 1, 64);
        s += __shfl_xor(s, 2, 64);
        if (part == 0) sq[g2] = s;
        // Afrag k=0..63 + Xf split-fp16 (formulas identical to old sqnorm)
        const size_t tt = (size_t)(g2 >> 4);
#pragma unroll
        for (int h = 0; h < 2; ++h) {
            const int cb = part * 2 + h;
            const float* mb = &ch[h * 8];
            uint4 pk;
            pk.x = f2bf_pair(mb[0], mb[1]);
            pk.y = f2bf_pair(mb[2], mb[3]);
            pk.z = f2bf_pair(mb[4], mb[5]);
            pk.w = f2bf_pair(mb[6], mb[7]);
            size_t af = (tt * 6 + (cb >> 2)) * 512 + (size_t)((cb & 3) * 16 + (g2 & 15)) * 8;
            *(uint4*)(Afrag + af) = pk;
            const int kf = cb >> 2;
            const int lanef = ((cb & 3) << 4) + (g2 & 15);
            __align__(16) _Float16 hbuf[8];
            __align__(16) _Float16 lbuf[8];
#pragma unroll
            for (int q2 = 0; q2 < 8; ++q2) {
                float v = mb[q2];
                _Float16 hi = (_Float16)v;
                hbuf[q2] = hi;
                lbuf[q2] = (_Float16)(v - (float)hi);
            }
            *(uint4*)(Xf + ((tt * 2 + kf) * 2 + 0) * 512 + (size_t)lanef * 8) = *(uint4*)hbuf;
            *(uint4*)(Xf + ((tt * 2 + kf) * 2 + 1) * 512 + (size_t)lanef * 8) = *(uint4*)lbuf;
        }
    }
}

// ---------------------------------------------------------------------------
// fused dist2sel v6 (blocks 0..1023) + u2v2 (blocks 1024..1151, 512-thread
// variant; R19-proven).
// ---------------------------------------------------------------------------
__global__ __launch_bounds__(512, 2) void dist2sel_kernel(
    const _Float16* __restrict__ Xf, const float* __restrict__ sq, int* __restrict__ idx,
    const float* __restrict__ x1, const float* __restrict__ Wcat, const float* __restrict__ b2,
    float* __restrict__ u2, float* __restrict__ v2)
{
    __shared__ unsigned kls[16 * 1024];   // 64 KB (union: u2v2 uses 50.7 KB)
    const int tid = threadIdx.x;

    if (blockIdx.x >= 1024) {
        // ----- u2v2 path -----
        float* aT  = (float*)kls;                       // [32][132]
        const int half = tid >> 8;                      // column half
        float* bW  = (float*)kls + 4224 + half * 4224;  // [32][132] per half
        const int t = tid & 255;
        const int m0 = (blockIdx.x - 1024) << 7;
        const int n0 = half << 7;
        const int ti = t >> 4, tj = t & 15;
        float acc[8][8];
#pragma unroll
        for (int a = 0; a < 8; ++a)
#pragma unroll
            for (int q = 0; q < 8; ++q) acc[a][q] = 0.f;
        for (int ct = 0; ct < 2; ++ct) {
            __syncthreads();
            if (half == 0) {
#pragma unroll
                for (int rep = 0; rep < 4; ++rep) {
                    int f = t + (rep << 8);
                    int r = f >> 3, q = f & 7;
                    float4 v = *(const float4*)(x1 + (size_t)(m0 + r) * 64 + ct * 32 + q * 4);
                    aT[(4 * q + 0) * 132 + r] = v.x; aT[(4 * q + 1) * 132 + r] = v.y;
                    aT[(4 * q + 2) * 132 + r] = v.z; aT[(4 * q + 3) * 132 + r] = v.w;
                }
            }
#pragma unroll
            for (int rep = 0; rep < 4; ++rep) {
                int f = t + (rep << 8);
                int cc = f >> 5, q = f & 31;
                *(float4*)&bW[cc * 132 + 4 * q] =
                    *(const float4*)(Wcat + (size_t)(ct * 32 + cc) * 256 + n0 + q * 4);
            }
            __syncthreads();
#pragma unroll 4
            for (int c = 0; c < 32; ++c) {
                float af[8], bf[8];
                *(float4*)&af[0] = *(const float4*)&aT[c * 132 + ti * 8];
                *(float4*)&af[4] = *(const float4*)&aT[c * 132 + ti * 8 + 4];
                *(float4*)&bf[0] = *(const float4*)&bW[c * 132 + tj * 8];
                *(float4*)&bf[4] = *(const float4*)&bW[c * 132 + tj * 8 + 4];
#pragma unroll
                for (int a = 0; a < 8; ++a)
#pragma unroll
                    for (int q = 0; q < 8; ++q) acc[a][q] = fmaf(af[a], bf[q], acc[a][q]);
            }
        }
#pragma unroll
        for (int a = 0; a < 8; ++a) {
            int m = m0 + ti * 8 + a;
            if (half == 0) {
                float outv[8];
#pragma unroll
                for (int q = 0; q < 8; ++q) outv[q] = acc[a][q];
                *(float4*)(u2 + (size_t)m * 128 + tj * 8)     = *(float4*)&outv[0];
                *(float4*)(u2 + (size_t)m * 128 + tj * 8 + 4) = *(float4*)&outv[4];
            } else {
                float outv[8];
#pragma unroll
                for (int q = 0; q < 8; ++q) outv[q] = acc[a][q] + b2[tj * 8 + q];
                *(float4*)(v2 + (size_t)m * 128 + tj * 8)     = *(float4*)&outv[0];
                *(float4*)(v2 + (size_t)m * 128 + tj * 8 + 4) = *(float4*)&outv[4];
            }
        }
        return;
    }

    // ----- dist2sel path (unchanged from R16/R18/R19) -----
    const int w = tid >> 6, lane = tid & 63;   // w in 0..7
    const int b = blockIdx.x >> 6;
    const int rowtile = blockIdx.x & 63;
    const int c15 = lane & 15;
    const int rbase = (lane >> 4) * 4;

    const f16x8* Xv = (const f16x8*)Xf;
    const int tA = b * 64 + rowtile;
    f16x8 ah[2], al[2];
#pragma unroll
    for (int kf = 0; kf < 2; ++kf) {
        ah[kf] = Xv[((size_t)(tA * 2 + kf) * 2 + 0) * 64 + lane];
        al[kf] = Xv[((size_t)(tA * 2 + kf) * 2 + 1) * 64 + lane];
    }
    const float* sqb = sq + (size_t)b * NP;
    float sqi[4];
#pragma unroll
    for (int rr = 0; rr < 4; ++rr)
        sqi[rr] = sqb[rowtile * 16 + rbase + rr];

    for (int q = 0; q < 8; ++q) {
        const int ct = w * 8 + q;
        const int tB = b * 64 + ct;
        f16x8 bh0 = Xv[((size_t)(tB * 2 + 0) * 2 + 0) * 64 + lane];
        f16x8 bl0 = Xv[((size_t)(tB * 2 + 0) * 2 + 1) * 64 + lane];
        f16x8 bh1 = Xv[((size_t)(tB * 2 + 1) * 2 + 0) * 64 + lane];
        f16x8 bl1 = Xv[((size_t)(tB * 2 + 1) * 2 + 1) * 64 + lane];
        const int col = ct * 16 + c15;
        const float sqj = sqb[col];
        f32x4 acc = (f32x4)0.0f;
        acc = __builtin_amdgcn_mfma_f32_16x16x32_f16(ah[0], bh0, acc, 0, 0, 0);
        acc = __builtin_amdgcn_mfma_f32_16x16x32_f16(ah[0], bl0, acc, 0, 0, 0);
        acc = __builtin_amdgcn_mfma_f32_16x16x32_f16(al[0], bh0, acc, 0, 0, 0);
        acc = __builtin_amdgcn_mfma_f32_16x16x32_f16(ah[1], bh1, acc, 0, 0, 0);
        acc = __builtin_amdgcn_mfma_f32_16x16x32_f16(ah[1], bl1, acc, 0, 0, 0);
        acc = __builtin_amdgcn_mfma_f32_16x16x32_f16(al[1], bh1, acc, 0, 0, 0);
        const int pc = col ^ ((col >> 6) & 15);   // bank swizzle (bijective per 64-col block)
#pragma unroll
        for (int rr = 0; rr < 4; ++rr) {
            float d = sqi[rr] + sqj - 2.0f * acc[rr];
            if (rowtile * 16 + rbase + rr == col) d += 1e10f;
            kls[(rbase + rr) * 1024 + pc] = monokey(d);
        }
    }
    __syncthreads();

    const int gb = b * NP;
    const int r0 = 2 * w, r1 = 2 * w + 1;
    unsigned* hrow0 = &kls[r0 * 1024];
    unsigned* hrow1 = &kls[r1 * 1024];
    unsigned long long perm0 = 0, perm1 = 0;
    {
        unsigned long long key[16];
#pragma unroll
        for (int s = 0; s < 16; ++s) {
            int col = (lane << 4) + s;
            int pc = col ^ ((col >> 6) & 15);
            key[s] = ((unsigned long long)kls[r0 * 1024 + pc] << 32) | (unsigned)col;
        }
        sort16_u64(key);
#pragma unroll
        for (int p = 0; p < 16; ++p) {
            hrow0[p * 64 + lane] = (unsigned)(key[p] >> 32);
            perm0 |= (unsigned long long)((unsigned)key[p] & 15u) << (4 * p);
        }
    }
    {
        unsigned long long key[16];
#pragma unroll
        for (int s = 0; s < 16; ++s) {
            int col = (lane << 4) + s;
            int pc = col ^ ((col >> 6) & 15);
            key[s] = ((unsigned long long)kls[r1 * 1024 + pc] << 32) | (unsigned)col;
        }
        sort16_u64(key);
#pragma unroll
        for (int p = 0; p < 16; ++p) {
            hrow1[p * 64 + lane] = (unsigned)(key[p] >> 32);
            perm1 |= (unsigned long long)((unsigned)key[p] & 15u) << (4 * p);
        }
    }
    dual_tourney20(hrow0, perm0, hrow1, perm1, lane,
                   idx + (size_t)(gb + rowtile * 16 + r0) * KNB,
                   idx + (size_t)(gb + rowtile * 16 + r1) * KNB, gb);
}

// ---------------------------------------------------------------------------
// conv2 gather-max -> Afrag k=64..191 (bf16 fragment layout), x2 never stored
// ---------------------------------------------------------------------------
__global__ __launch_bounds__(256) void gatherfrag_kernel(
    const int* __restrict__ idx, const float* __restrict__ u2,
    const float* __restrict__ v2, ushortT* __restrict__ Afrag)
{
    const int tid = threadIdx.x;
    const int i = blockIdx.x * 16 + (tid >> 4);
    const int cb = tid & 15;
    const int* ib = idx + (size_t)i * KNB;
    float m[8];
#pragma unroll
    for (int d = 0; d < 8; ++d) m[d] = -3e38f;
    for (int e = 0; e < KNB; ++e) {
        int j = ib[e];
        const float4* p = (const float4*)(u2 + (size_t)j * 128 + cb * 8);
        float4 a = p[0], b = p[1];
        m[0] = fmaxf(m[0], a.x); m[1] = fmaxf(m[1], a.y); m[2] = fmaxf(m[2], a.z); m[3] = fmaxf(m[3], a.w);
        m[4] = fmaxf(m[4], b.x); m[5] = fmaxf(m[5], b.y); m[6] = fmaxf(m[6], b.z); m[7] = fmaxf(m[7], b.w);
    }
    const float4* vp = (const float4*)(v2 + (size_t)i * 128 + cb * 8);
    float4 va = vp[0], vb = vp[1];
    m[0] += va.x; m[1] += va.y; m[2] += va.z; m[3] += va.w;
    m[4] += vb.x; m[5] += vb.y; m[6] += vb.z; m[7] += vb.w;
    uint4 pk;
    pk.x = f2bf_pair(m[0], m[1]);
    pk.y = f2bf_pair(m[2], m[3]);
    pk.z = f2bf_pair(m[4], m[5]);
    pk.w = f2bf_pair(m[6], m[7]);
    size_t af = ((size_t)(i >> 4) * 6 + 2 + (cb >> 2)) * 512 + (size_t)((cb & 3) * 16 + (i & 15)) * 8;
    *(uint4*)(Afrag + af) = pk;
}

// ---------------------------------------------------------------------------
// lin1 + global max pool via bf16 MFMA.
// ---------------------------------------------------------------------------
__global__ __launch_bounds__(256) void lin1max_mfma_kernel(
    const ushortT* __restrict__ Afrag, const ushortT* __restrict__ Wlb, float* __restrict__ gp)
{
    __shared__ float red[4][128];
    const int tid = threadIdx.x;
    const int w = tid >> 6, lane = tid & 63;
    const int nt = blockIdx.x & 7;
    const int rt = (blockIdx.x >> 3) & 7;
    const int b  = blockIdx.x >> 6;
    const int rt16 = ((b << 3) + rt) * 8 + (w << 1);
    const bf16x8* Ap = (const bf16x8*)Afrag;
    const bf16x8* Bp = (const bf16x8*)Wlb;
    f32x4 acc[2][8];
#pragma unroll
    for (int mm = 0; mm < 2; ++mm)
#pragma unroll
        for (int f = 0; f < 8; ++f) acc[mm][f] = (f32x4)0.0f;
#pragma unroll
    for (int s = 0; s < 6; ++s) {
        bf16x8 a0 = Ap[((rt16    ) * 6 + s) * 64 + lane];
        bf16x8 a1 = Ap[((rt16 + 1) * 6 + s) * 64 + lane];
#pragma unroll
        for (int f = 0; f < 8; ++f) {
            bf16x8 bb = Bp[(((nt * 6 + s) << 3) + f) * 64 + lane];
            acc[0][f] = __builtin_amdgcn_mfma_f32_16x16x32_bf16(a0, bb, acc[0][f], 0, 0, 0);
            acc[1][f] = __builtin_amdgcn_mfma_f32_16x16x32_bf16(a1, bb, acc[1][f], 0, 0, 0);
        }
    }
#pragma unroll
    for (int f = 0; f < 8; ++f) {
        float m = acc[0][f][0];
        m = fmaxf(m, acc[0][f][1]); m = fmaxf(m, acc[0][f][2]); m = fmaxf(m, acc[0][f][3]);
        m = fmaxf(m, acc[1][f][0]); m = fmaxf(m, acc[1][f][1]);
        m = fmaxf(m, acc[1][f][2]); m = fmaxf(m, acc[1][f][3]);
        m = fmaxf(m, __shfl_xor(m, 16, 64));
        m = fmaxf(m, __shfl_xor(m, 32, 64));
        if (lane < 16) red[w][f * 16 + lane] = m;
    }
    __syncthreads();
    if (tid < 128) {
        float m = fmaxf(fmaxf(red[0][tid], red[1][tid]), fmaxf(red[2][tid], red[3][tid]));
        gp[((size_t)rt * NB + b) * 1024 + nt * 128 + tid] = m;
    }
}

// ---------------------------------------------------------------------------
// head stage 0: gs[b][c] = max over 8 gp parts + bl[c]   (16x1024)
// ---------------------------------------------------------------------------
__global__ __launch_bounds__(256) void gmax_kernel(
    const float* __restrict__ gp, const float* __restrict__ bl, float* __restrict__ gs)
{
    int id = blockIdx.x * 256 + threadIdx.x;   // 16384
    int b = id >> 10, c = id & 1023;
    float m = gp[(size_t)b * 1024 + c];
#pragma unroll
    for (int part = 1; part < 8; ++part)
        m = fmaxf(m, gp[((size_t)part * NB + b) * 1024 + c]);
    gs[(size_t)b * 1024 + c] = m + bl[c];
}

// ---------------------------------------------------------------------------
// head stage 1: h1[b][j] = relu(gs[b] . Wm1T[j] + bm1[j]); one block per j.
// ---------------------------------------------------------------------------
__global__ __launch_bounds__(256) void head1_kernel(
    const float* __restrict__ gs, const float* __restrict__ Wm1T, const float* __restrict__ bm1,
    float* __restrict__ h1)
{
    __shared__ float red[16][17];
    const int j = blockIdx.x;                  // 0..511
    const int t = threadIdx.x;
    const int b = t >> 4, seg = t & 15;
    const float4* wr = (const float4*)(Wm1T + (size_t)j * 1024 + seg * 64);
    const float4* gr = (const float4*)(gs + (size_t)b * 1024 + seg * 64);
    float acc = 0.f;
#pragma unroll
    for (int q = 0; q < 16; ++q) {
        float4 w = wr[q], g = gr[q];
        acc = fmaf(w.x, g.x, acc); acc = fmaf(w.y, g.y, acc);
        acc = fmaf(w.z, g.z, acc); acc = fmaf(w.w, g.w, acc);
    }
    red[b][seg] = acc;
    __syncthreads();
    if (t < 16) {
        float s = 0.f;
#pragma unroll
        for (int k = 0; k < 16; ++k) s += red[t][k];
        h1[(size_t)t * 512 + j] = fmaxf(s + bm1[j], 0.f);
    }
}

// ---------------------------------------------------------------------------
// head stage 2: h2[b][j] = relu(h1[b] . Wm2T[j] + bm2[j]); one block per j.
// ---------------------------------------------------------------------------
__global__ __launch_bounds__(256) void head2_kernel(
    const float* __restrict__ h1, const float* __restrict__ Wm2T, const float* __restrict__ bm2,
    float* __restrict__ h2)
{
    __shared__ float red[16][17];
    const int j = blockIdx.x;                  // 0..255
    const int t = threadIdx.x;
    const int b = t >> 4, seg = t & 15;
    const float4* wr = (const float4*)(Wm2T + (size_t)j * 512 + seg * 32);
    const float4* hr = (const float4*)(h1 + (size_t)b * 512 + seg * 32);
    float acc = 0.f;
#pragma unroll
    for (int q = 0; q < 8; ++q) {
        float4 w = wr[q], g = hr[q];
        acc = fmaf(w.x, g.x, acc); acc = fmaf(w.y, g.y, acc);
        acc = fmaf(w.z, g.z, acc); acc = fmaf(w.w, g.w, acc);
    }
    red[b][seg] = acc;
    __syncthreads();
    if (t < 16) {
        float s = 0.f;
#pragma unroll
        for (int k = 0; k < 16; ++k) s += red[t][k];
        h2[(size_t)t * 256 + j] = fmaxf(s + bm2[j], 0.f);
    }
}

// ---------------------------------------------------------------------------
// head stage 3: logits + log_softmax; one block per batch.
// ---------------------------------------------------------------------------
__global__ __launch_bounds__(256) void head3_kernel(
    const float* __restrict__ h2, const float* __restrict__ Wm3T, const float* __restrict__ bm3,
    float* __restrict__ out)
{
    __shared__ float lg[64];
    const int tid = threadIdx.x;
    const int b = blockIdx.x;
    if (tid < 40) {
        float acc = bm3[tid];
        const float4* wr = (const float4*)(Wm3T + (size_t)tid * 256);
        const float4* hr = (const float4*)(h2 + (size_t)b * 256);
#pragma unroll
        for (int c4 = 0; c4 < 64; ++c4) {
            float4 w = wr[c4];
            float4 g4 = hr[c4];
            acc = fmaf(w.x, g4.x, acc); acc = fmaf(w.y, g4.y, acc);
            acc = fmaf(w.z, g4.z, acc); acc = fmaf(w.w, g4.w, acc);
        }
        lg[tid] = acc;
    }
    __syncthreads();
    if (tid < 64) {
        float v = (tid < 40) ? lg[tid] : -3e38f;
        float m = v;
        for (int off = 32; off; off >>= 1) m = fmaxf(m, __shfl_xor(m, off, 64));
        float ex = (tid < 40) ? expf(v - m) : 0.f;
        float s = ex;
        for (int off = 32; off; off >>= 1) s += __shfl_xor(s, off, 64);
        if (tid < 40) out[b * 40 + tid] = v - m - logf(s);
    }
}

// ---------------------------------------------------------------------------
extern "C" void kernel_launch(void* const* d_in, const int* in_sizes, int n_in,
                              void* d_out, int out_size, void* d_ws, size_t ws_size,
                              hipStream_t stream)
{
    const float* pos = (const float*)d_in[0];
    const float* W1a = (const float*)d_in[1];
    const float* b1a = (const float*)d_in[2];
    const float* W1b = (const float*)d_in[3];
    const float* b1b = (const float*)d_in[4];
    const float* W1c = (const float*)d_in[5];
    const float* b1c = (const float*)d_in[6];
    const float* W2  = (const float*)d_in[7];
    const float* b2  = (const float*)d_in[8];
    const float* Wl  = (const float*)d_in[9];
    const float* bl  = (const float*)d_in[10];
    const float* Wm1 = (const float*)d_in[11];
    const float* bm1 = (const float*)d_in[12];
    const float* Wm2 = (const float*)d_in[13];
    const float* bm2 = (const float*)d_in[14];
    const float* Wm3 = (const float*)d_in[15];
    const float* bm3 = (const float*)d_in[16];
    float* out = (float*)d_out;

    char* ws = (char*)d_ws;
    const size_t MB = 1024 * 1024;
    size_t off = 0;
    auto alloc = [&](size_t bytes) { size_t o = off; off += (bytes + 255) & ~(size_t)255; return o; };
    size_t u2_off  = alloc(8 * MB);          // u1 (4MB) then u2 (8MB)
    size_t v2_off  = alloc(8 * MB);          // v1 (4MB) then v2 (8MB)
    size_t x1_off  = alloc(4 * MB);
    size_t idx_off = alloc((size_t)NPT * KNB * 4);
    size_t sq_off  = alloc((size_t)NPT * 4);
    size_t gp_off  = alloc((size_t)8 * NB * 1024 * 4);
    size_t gs_off  = alloc((size_t)NB * 1024 * 4);
    size_t h1_off  = alloc((size_t)NB * 512 * 4);
    size_t h2_off  = alloc((size_t)NB * 256 * 4);
    size_t wc_off  = alloc(64 * 256 * 4);
    size_t w1t_off = alloc(512 * 1024 * 4);
    size_t w2t_off = alloc(256 * 512 * 4);
    size_t w3t_off = alloc(40 * 256 * 4);
    size_t af_off  = alloc((size_t)(NPT / 16) * 6 * 512 * 2);  // 6 MB bf16 A-fragments
    size_t wlb_off = alloc((size_t)8 * 6 * 8 * 512 * 2);       // 384 KB bf16 Wl fragments
    size_t wcf_off = alloc((size_t)16384 * 2);                 // 32 KB split-fp16 conv1 W frags
    size_t xf_off  = alloc((size_t)(NPT / 16) * 2 * 2 * 512 * 2); // 4 MB split-fp16 x1 frags
    if (ws_size < off) { fail_kernel<<<3, 256, 0, stream>>>(out, out_size); return; }

    float* u1    = (float*)(ws + u2_off);
    float* v1    = (float*)(ws + v2_off);
    float* u2    = (float*)(ws + u2_off);
    float* v2    = (float*)(ws + v2_off);
    float* x1    = (float*)(ws + x1_off);
    int*   idx   = (int*)(ws + idx_off);
    float* sq    = (float*)(ws + sq_off);
    float* gp    = (float*)(ws + gp_off);
    float* gs    = (float*)(ws + gs_off);
    float* h1    = (float*)(ws + h1_off);
    float* h2    = (float*)(ws + h2_off);
    float* Wcat  = (float*)(ws + wc_off);
    float* Wm1T  = (float*)(ws + w1t_off);
    float* Wm2T  = (float*)(ws + w2t_off);
    float* Wm3T  = (float*)(ws + w3t_off);
    ushortT* Afrag = (ushortT*)(ws + af_off);
    ushortT* Wlb   = (ushortT*)(ws + wlb_off);
    _Float16* Wc1f = (_Float16*)(ws + wcf_off);
    _Float16* Xf   = (_Float16*)(ws + xf_off);

    phase1_kernel<<<11688, 256, 0, stream>>>(pos, W1a, b1a, W2, Wm1, Wm2, Wm3, Wl, W1b, W1c,
                                             idx, u1, v1, Wcat, Wm1T, Wm2T, Wm3T, Wlb, Wc1f);
    conv1_mfma_kernel<<<1024, 64, 0, stream>>>(idx, u1, v1, Wc1f, b1b, b1c, x1, sq, Afrag, Xf);
    dist2sel_kernel<<<1152, 512, 0, stream>>>(Xf, sq, idx, x1, Wcat, b2, u2, v2);
    gatherfrag_kernel<<<1024, 256, 0, stream>>>(idx, u2, v2, Afrag);
    lin1max_mfma_kernel<<<1024, 256, 0, stream>>>(Afrag, Wlb, gp);
    gmax_kernel<<<64, 256, 0, stream>>>(gp, bl, gs);
    head1_kernel<<<512, 256, 0, stream>>>(gs, Wm1T, bm1, h1);
    head2_kernel<<<256, 256, 0, stream>>>(h1, Wm2T, bm2, h2);
    head3_kernel<<<16, 256, 0, stream>>>(h2, Wm3T, bm3, out);
}